// Round 1
// baseline (3834.702 us; speedup 1.0000x reference)
//
#include <hip/hip_runtime.h>
#include <math.h>

// Problem constants (match reference)
#define V_  50257
#define D_  768
#define S_  16
#define NL_ 4
#define B_  2
#define L_  512
#define EPS_ 1e-5f

static constexpr int BLD  = B_ * L_ * D_;     // 786432
static constexpr int ROWS = B_ * L_;          // 1024

// ---------------------------------------------------------------------------
// Embedding gather: x[b,l,:] = emb[tokens[b,l],:]
// ---------------------------------------------------------------------------
__global__ __launch_bounds__(256)
void emb_kernel(const int* __restrict__ tok, const float* __restrict__ emb,
                float* __restrict__ x) {
    int i = blockIdx.x * 256 + threadIdx.x;      // over B*L*D
    if (i >= BLD) return;
    int d  = i % D_;
    int bl = i / D_;
    x[i] = emb[(size_t)tok[bl] * D_ + d];
}

// ---------------------------------------------------------------------------
// LayerNorm: one block (256 thr) per row of 768.
// ---------------------------------------------------------------------------
__global__ __launch_bounds__(256)
void ln_kernel(const float* __restrict__ x, const float* __restrict__ g,
               const float* __restrict__ b, float* __restrict__ o) {
    int row = blockIdx.x;
    const float* xr = x + (size_t)row * D_;
    int t = threadIdx.x;
    float v0 = xr[t], v1 = xr[t + 256], v2 = xr[t + 512];
    float s1 = v0 + v1 + v2;
    float s2 = v0 * v0 + v1 * v1 + v2 * v2;
    // wave64 reduce
    for (int off = 32; off > 0; off >>= 1) {
        s1 += __shfl_down(s1, off);
        s2 += __shfl_down(s2, off);
    }
    __shared__ float red[8];
    __shared__ float mv[2];
    int wave = t >> 6, lane = t & 63;
    if (lane == 0) { red[wave] = s1; red[4 + wave] = s2; }
    __syncthreads();
    if (t == 0) {
        float a = red[0] + red[1] + red[2] + red[3];
        float c = red[4] + red[5] + red[6] + red[7];
        float mean = a / (float)D_;
        float var  = c / (float)D_ - mean * mean;
        mv[0] = mean;
        mv[1] = 1.f / sqrtf(var + EPS_);
    }
    __syncthreads();
    float mean = mv[0], inv = mv[1];
    float* orow = o + (size_t)row * D_;
    orow[t]       = (v0 - mean) * inv * g[t]       + b[t];
    orow[t + 256] = (v1 - mean) * inv * g[t + 256] + b[t + 256];
    orow[t + 512] = (v2 - mean) * inv * g[t + 512] + b[t + 512];
}

// ---------------------------------------------------------------------------
// Depthwise conv (width 3, zero pad) + bias + SiLU.
// Input xi is the first D_ channels of xr rows (stride 2*D_).
// ---------------------------------------------------------------------------
__global__ __launch_bounds__(256)
void conv_silu_kernel(const float* __restrict__ xr, const float* __restrict__ cw,
                      const float* __restrict__ cb, float* __restrict__ xc) {
    int i = blockIdx.x * 256 + threadIdx.x;      // over B*L*D
    if (i >= BLD) return;
    int d  = i % D_;
    int bl = i / D_;
    int l  = bl % L_;
    const size_t stride = 2 * D_;
    float xm = (l > 0)      ? xr[(size_t)(bl - 1) * stride + d] : 0.f;
    float x0 =                xr[(size_t)bl * stride + d];
    float xp = (l < L_ - 1) ? xr[(size_t)(bl + 1) * stride + d] : 0.f;
    float v = xm * cw[d * 3 + 0] + x0 * cw[d * 3 + 1] + xp * cw[d * 3 + 2] + cb[d];
    xc[i] = v / (1.f + expf(-v));                // SiLU
}

// ---------------------------------------------------------------------------
// Selective-scan: thread per (b,d,s); s is the fastest dim -> 16-lane groups.
// y[b,l,d] = (sum_s h) * D_param[d] * silu(res[b,l,d])
// ---------------------------------------------------------------------------
__global__ __launch_bounds__(256)
void scan_kernel(const float* __restrict__ dt, const float* __restrict__ xc,
                 const float* __restrict__ xr, const float* __restrict__ A_log,
                 const float* __restrict__ Dp, float* __restrict__ y) {
    int t = blockIdx.x * 256 + threadIdx.x;      // over B*D*S
    int s = t & (S_ - 1);
    int d = (t >> 4) % D_;
    int b = t / (D_ * S_);
    float a  = -expf(A_log[d * S_ + s]);
    float Dd = Dp[d];
    const float* dtp = dt + (size_t)b * L_ * D_ + d;
    const float* xcp = xc + (size_t)b * L_ * D_ + d;
    const float* rsp = xr + (size_t)b * L_ * 2 * D_ + D_ + d;  // res part
    float* yp = y + (size_t)b * L_ * D_ + d;
    float h = 0.f;
    float dtv = dtp[0], xcv = xcp[0], rv = rsp[0];
    for (int l = 0; l < L_; ++l) {
        float dtn = 0.f, xcn = 0.f, rn = 0.f;
        if (l + 1 < L_) {                       // prefetch next step
            dtn = dtp[(size_t)(l + 1) * D_];
            xcn = xcp[(size_t)(l + 1) * D_];
            rn  = rsp[(size_t)(l + 1) * 2 * D_];
        }
        h = h * expf(a * dtv) + xcv;
        float ys = h;
        ys += __shfl_xor(ys, 1, 16);
        ys += __shfl_xor(ys, 2, 16);
        ys += __shfl_xor(ys, 4, 16);
        ys += __shfl_xor(ys, 8, 16);
        if (s == 0) {
            float sil = rv / (1.f + expf(-rv));
            yp[(size_t)l * D_] = ys * Dd * sil;
        }
        dtv = dtn; xcv = xcn; rv = rn;
    }
}

// ---------------------------------------------------------------------------
// FP32 GEMM: C[M,N] = A[M,K] @ W[N,K]^T  (both K-contiguous)
// 128x128 tile, BK=16, 256 threads, 8x8 microtile, transposed LDS.
// EPI: 0 = plain store, 1 = sigmoid(v + bias[col]), 2 = v + resid[row*N+col]
// M must be a multiple of 128; N,K arbitrary... K must be multiple of 16.
// ---------------------------------------------------------------------------
#define BM 128
#define BN 128
#define BK 16

template <int EPI>
__global__ __launch_bounds__(256)
void gemm_wt(const float* __restrict__ A, const float* __restrict__ W,
             const float* __restrict__ bias, const float* __restrict__ resid,
             float* __restrict__ C, int M, int N, int K) {
    __shared__ float As[BK][BM + 4];
    __shared__ float Ws[BK][BN + 4];
    const int tid = threadIdx.x;
    const int bm = blockIdx.y * BM;
    const int bn = blockIdx.x * BN;
    const int tx = tid & 15, ty = tid >> 4;

    const int lrow = tid >> 1;          // 0..127
    const int lk   = (tid & 1) * 8;     // 0 or 8

    float acc[8][8];
#pragma unroll
    for (int i = 0; i < 8; ++i)
#pragma unroll
        for (int j = 0; j < 8; ++j) acc[i][j] = 0.f;

    for (int k0 = 0; k0 < K; k0 += BK) {
        const float* ap = A + (size_t)(bm + lrow) * K + k0 + lk;
        float4 av0 = *(const float4*)ap;
        float4 av1 = *(const float4*)(ap + 4);
        float4 wv0 = {0, 0, 0, 0}, wv1 = {0, 0, 0, 0};
        int wrow = bn + lrow;
        if (wrow < N) {
            const float* wp = W + (size_t)wrow * K + k0 + lk;
            wv0 = *(const float4*)wp;
            wv1 = *(const float4*)(wp + 4);
        }
        __syncthreads();   // protect previous tile reads
        As[lk + 0][lrow] = av0.x; As[lk + 1][lrow] = av0.y;
        As[lk + 2][lrow] = av0.z; As[lk + 3][lrow] = av0.w;
        As[lk + 4][lrow] = av1.x; As[lk + 5][lrow] = av1.y;
        As[lk + 6][lrow] = av1.z; As[lk + 7][lrow] = av1.w;
        Ws[lk + 0][lrow] = wv0.x; Ws[lk + 1][lrow] = wv0.y;
        Ws[lk + 2][lrow] = wv0.z; Ws[lk + 3][lrow] = wv0.w;
        Ws[lk + 4][lrow] = wv1.x; Ws[lk + 5][lrow] = wv1.y;
        Ws[lk + 6][lrow] = wv1.z; Ws[lk + 7][lrow] = wv1.w;
        __syncthreads();
#pragma unroll
        for (int k = 0; k < BK; ++k) {
            float4 a0 = *(const float4*)&As[k][ty * 8];
            float4 a1 = *(const float4*)&As[k][ty * 8 + 4];
            float4 w0 = *(const float4*)&Ws[k][tx * 8];
            float4 w1 = *(const float4*)&Ws[k][tx * 8 + 4];
            float av[8] = {a0.x, a0.y, a0.z, a0.w, a1.x, a1.y, a1.z, a1.w};
            float wv[8] = {w0.x, w0.y, w0.z, w0.w, w1.x, w1.y, w1.z, w1.w};
#pragma unroll
            for (int i = 0; i < 8; ++i)
#pragma unroll
                for (int j = 0; j < 8; ++j)
                    acc[i][j] = fmaf(av[i], wv[j], acc[i][j]);
        }
    }

    // epilogue
#pragma unroll
    for (int i = 0; i < 8; ++i) {
        int row = bm + ty * 8 + i;
#pragma unroll
        for (int j = 0; j < 8; ++j) {
            int col = bn + tx * 8 + j;
            if (col < N) {
                float v = acc[i][j];
                if (EPI == 1) v = 1.f / (1.f + expf(-(v + bias[col])));
                if (EPI == 2) v = v + resid[(size_t)row * N + col];
                C[(size_t)row * N + col] = v;
            }
        }
    }
}

// ---------------------------------------------------------------------------
// Host launcher
// ---------------------------------------------------------------------------
extern "C" void kernel_launch(void* const* d_in, const int* in_sizes, int n_in,
                              void* d_out, int out_size, void* d_ws, size_t ws_size,
                              hipStream_t stream) {
    (void)in_sizes; (void)n_in; (void)out_size; (void)ws_size;
    const int*   tokens  = (const int*)  d_in[0];
    const float* emb     = (const float*)d_in[1];
    const float* ln_g    = (const float*)d_in[2];
    const float* ln_b    = (const float*)d_in[3];
    const float* in_w    = (const float*)d_in[4];
    const float* conv_w  = (const float*)d_in[5];
    const float* conv_b  = (const float*)d_in[6];
    const float* dt_w    = (const float*)d_in[7];
    const float* dt_b    = (const float*)d_in[8];
    const float* A_log   = (const float*)d_in[9];
    const float* D_param = (const float*)d_in[10];
    const float* out_w   = (const float*)d_in[11];
    const float* lnf_g   = (const float*)d_in[12];
    const float* lnf_b   = (const float*)d_in[13];
    const float* head_w  = (const float*)d_in[14];
    float* out = (float*)d_out;

    // workspace carve (floats)
    float* x  = (float*)d_ws;            // BLD
    float* xn = x  + BLD;                // BLD  (also reused as y)
    float* xr = xn + BLD;                // 2*BLD
    float* xc = xr + 2 * BLD;            // BLD
    float* dt = xc + BLD;                // BLD
    float* y  = xn;                      // alias: xn dead after in_proj GEMM

    emb_kernel<<<(BLD + 255) / 256, 256, 0, stream>>>(tokens, emb, x);

    for (int l = 0; l < NL_; ++l) {
        const float* lg  = ln_g   + (size_t)l * D_;
        const float* lb  = ln_b   + (size_t)l * D_;
        const float* iw  = in_w   + (size_t)l * 2 * D_ * D_;
        const float* cw  = conv_w + (size_t)l * D_ * 3;
        const float* cb  = conv_b + (size_t)l * D_;
        const float* dw  = dt_w   + (size_t)l * D_ * D_;
        const float* db  = dt_b   + (size_t)l * D_;
        const float* al  = A_log  + (size_t)l * D_ * S_;
        const float* dp  = D_param+ (size_t)l * D_;
        const float* ow  = out_w  + (size_t)l * D_ * D_;

        ln_kernel<<<ROWS, 256, 0, stream>>>(x, lg, lb, xn);
        gemm_wt<0><<<dim3((2 * D_) / BN, ROWS / BM), 256, 0, stream>>>(
            xn, iw, nullptr, nullptr, xr, ROWS, 2 * D_, D_);
        conv_silu_kernel<<<(BLD + 255) / 256, 256, 0, stream>>>(xr, cw, cb, xc);
        gemm_wt<1><<<dim3(D_ / BN, ROWS / BM), 256, 0, stream>>>(
            xc, dw, db, nullptr, dt, ROWS, D_, D_);
        scan_kernel<<<(B_ * D_ * S_) / 256, 256, 0, stream>>>(
            dt, xc, xr, al, dp, y);
        gemm_wt<2><<<dim3(D_ / BN, ROWS / BM), 256, 0, stream>>>(
            y, ow, nullptr, x, x, ROWS, D_, D_);
    }

    ln_kernel<<<ROWS, 256, 0, stream>>>(x, lnf_g, lnf_b, xn);
    gemm_wt<0><<<dim3((V_ + BN - 1) / BN, ROWS / BM), 256, 0, stream>>>(
        xn, head_w, nullptr, nullptr, out, ROWS, V_, D_);
}

// Round 4
// 2021.294 us; speedup vs baseline: 1.8972x; 1.8972x over previous
//
#include <hip/hip_runtime.h>
#include <math.h>

// Problem constants (match reference)
#define V_  50257
#define D_  768
#define S_  16
#define NL_ 4
#define B_  2
#define L_  512
#define EPS_ 1e-5f

static constexpr int BLD  = B_ * L_ * D_;     // 786432
static constexpr int ROWS = B_ * L_;          // 1024
static constexpr int VPAD = 50304;            // V_ rounded up to 128

typedef __bf16 bf16x8 __attribute__((ext_vector_type(8)));
typedef __bf16 bf16x4 __attribute__((ext_vector_type(4)));
typedef float  f32x4  __attribute__((ext_vector_type(4)));

// ---------------------------------------------------------------------------
// Embedding gather
// ---------------------------------------------------------------------------
__global__ __launch_bounds__(256)
void emb_kernel(const int* __restrict__ tok, const float* __restrict__ emb,
                float* __restrict__ x) {
    int i = blockIdx.x * 256 + threadIdx.x;
    if (i >= BLD) return;
    int d  = i % D_;
    int bl = i / D_;
    x[i] = emb[(size_t)tok[bl] * D_ + d];
}

// ---------------------------------------------------------------------------
// LayerNorm: one block (256 thr) per row of 768.
// ---------------------------------------------------------------------------
__global__ __launch_bounds__(256)
void ln_kernel(const float* __restrict__ x, const float* __restrict__ g,
               const float* __restrict__ b, float* __restrict__ o) {
    int row = blockIdx.x;
    const float* xr = x + (size_t)row * D_;
    int t = threadIdx.x;
    float v0 = xr[t], v1 = xr[t + 256], v2 = xr[t + 512];
    float s1 = v0 + v1 + v2;
    float s2 = v0 * v0 + v1 * v1 + v2 * v2;
    for (int off = 32; off > 0; off >>= 1) {
        s1 += __shfl_down(s1, off);
        s2 += __shfl_down(s2, off);
    }
    __shared__ float red[8];
    __shared__ float mv[2];
    int wave = t >> 6, lane = t & 63;
    if (lane == 0) { red[wave] = s1; red[4 + wave] = s2; }
    __syncthreads();
    if (t == 0) {
        float a = red[0] + red[1] + red[2] + red[3];
        float c = red[4] + red[5] + red[6] + red[7];
        float mean = a / (float)D_;
        float var  = c / (float)D_ - mean * mean;
        mv[0] = mean;
        mv[1] = 1.f / sqrtf(var + EPS_);
    }
    __syncthreads();
    float mean = mv[0], inv = mv[1];
    float* orow = o + (size_t)row * D_;
    orow[t]       = (v0 - mean) * inv * g[t]       + b[t];
    orow[t + 256] = (v1 - mean) * inv * g[t + 256] + b[t + 256];
    orow[t + 512] = (v2 - mean) * inv * g[t + 512] + b[t + 512];
}

// ---------------------------------------------------------------------------
// Depthwise conv (width 3, zero pad) + bias + SiLU.
// ---------------------------------------------------------------------------
__global__ __launch_bounds__(256)
void conv_silu_kernel(const float* __restrict__ xr, const float* __restrict__ cw,
                      const float* __restrict__ cb, float* __restrict__ xc) {
    int i = blockIdx.x * 256 + threadIdx.x;
    if (i >= BLD) return;
    int d  = i % D_;
    int bl = i / D_;
    int l  = bl % L_;
    const size_t stride = 2 * D_;
    float xm = (l > 0)      ? xr[(size_t)(bl - 1) * stride + d] : 0.f;
    float x0 =                xr[(size_t)bl * stride + d];
    float xp = (l < L_ - 1) ? xr[(size_t)(bl + 1) * stride + d] : 0.f;
    float v = xm * cw[d * 3 + 0] + x0 * cw[d * 3 + 1] + xp * cw[d * 3 + 2] + cb[d];
    xc[i] = v / (1.f + __expf(-v));
}

// ---------------------------------------------------------------------------
// Selective scan: thread per (b,d,s)
// ---------------------------------------------------------------------------
__global__ __launch_bounds__(256)
void scan_kernel(const float* __restrict__ dt, const float* __restrict__ xc,
                 const float* __restrict__ xr, const float* __restrict__ A_log,
                 const float* __restrict__ Dp, float* __restrict__ y) {
    int t = blockIdx.x * 256 + threadIdx.x;
    int s = t & (S_ - 1);
    int d = (t >> 4) % D_;
    int b = t / (D_ * S_);
    float a  = -__expf(A_log[d * S_ + s]);
    float Dd = Dp[d];
    const float* dtp = dt + (size_t)b * L_ * D_ + d;
    const float* xcp = xc + (size_t)b * L_ * D_ + d;
    const float* rsp = xr + (size_t)b * L_ * 2 * D_ + D_ + d;
    float* yp = y + (size_t)b * L_ * D_ + d;
    float h = 0.f;
    float dtv = dtp[0], xcv = xcp[0], rv = rsp[0];
    for (int l = 0; l < L_; ++l) {
        float dtn = 0.f, xcn = 0.f, rn = 0.f;
        if (l + 1 < L_) {
            dtn = dtp[(size_t)(l + 1) * D_];
            xcn = xcp[(size_t)(l + 1) * D_];
            rn  = rsp[(size_t)(l + 1) * 2 * D_];
        }
        h = h * __expf(a * dtv) + xcv;
        float ys = h;
        ys += __shfl_xor(ys, 1, 16);
        ys += __shfl_xor(ys, 2, 16);
        ys += __shfl_xor(ys, 4, 16);
        ys += __shfl_xor(ys, 8, 16);
        if (s == 0) {
            float sil = rv / (1.f + __expf(-rv));
            yp[(size_t)l * D_] = ys * Dd * sil;
        }
        dtv = dtn; xcv = xcn; rv = rn;
    }
}

// ---------------------------------------------------------------------------
// fp32 -> (hi, lo) bf16 split, float4-vectorized. i >= n4 -> zero fill (pad).
// ---------------------------------------------------------------------------
__global__ __launch_bounds__(256)
void split4_kernel(const float* __restrict__ x, __bf16* __restrict__ hi,
                   __bf16* __restrict__ lo, int n4, int npad4) {
    int i = blockIdx.x * 256 + threadIdx.x;
    if (i >= npad4) return;
    float4 v = {0.f, 0.f, 0.f, 0.f};
    if (i < n4) v = ((const float4*)x)[i];
    bf16x4 h, l;
    h[0] = (__bf16)v.x; h[1] = (__bf16)v.y; h[2] = (__bf16)v.z; h[3] = (__bf16)v.w;
    l[0] = (__bf16)(v.x - (float)h[0]);
    l[1] = (__bf16)(v.y - (float)h[1]);
    l[2] = (__bf16)(v.z - (float)h[2]);
    l[3] = (__bf16)(v.w - (float)h[3]);
    *(bf16x4*)&hi[(size_t)i * 4] = h;
    *(bf16x4*)&lo[(size_t)i * 4] = l;
}

// ---------------------------------------------------------------------------
// Split-bf16 MFMA GEMM: C[M,N] = A[M,K] @ W[N,K]^T in ~fp32 precision via
// A_hi*W_hi + A_lo*W_hi + A_hi*W_lo. m97-style structure: global_load_lds
// staging, 2 barriers per K-step, 16x16x32 MFMA.
// 256 threads = 4 waves in 2x2; wave tile (BM/2)x(BN/2).
// EPI: 0 plain, 1 sigmoid(v+bias[col]), 2 v+resid[row*N+col]
// ---------------------------------------------------------------------------
template <int BMt, int BNt, int EPI>
__global__ __launch_bounds__(256)
void gemm_mfma(const __bf16* __restrict__ Ahi, const __bf16* __restrict__ Alo,
               const __bf16* __restrict__ Whi, const __bf16* __restrict__ Wlo,
               const float* __restrict__ bias, const float* __restrict__ resid,
               float* __restrict__ C, int M, int N, int K) {
    constexpr int BK = 32;
    constexpr int FR = BMt / 32;    // A frags per wave
    constexpr int FC = BNt / 32;    // B frags per wave
    __shared__ __bf16 As[BMt * BK];
    __shared__ __bf16 Ws[BNt * BK];
    const int tid  = threadIdx.x;
    const int lane = tid & 63;
    const int wv   = tid >> 6;
    const int wr   = wv >> 1, wc = wv & 1;
    const int bm   = blockIdx.y * BMt;
    const int bn   = blockIdx.x * BNt;

    // staging map: byte o = issue*4096 + tid*16 -> row o>>6, col (o&63)>>1
    const int srow = tid >> 2;
    const int scol = (tid & 3) * 8;

    f32x4 acc[FR][FC] = {};

    const int arow = wr * (BMt / 2) + (lane & 15);
    const int brow = wc * (BNt / 2) + (lane & 15);
    const int kof  = (lane >> 4) * 8;

#pragma unroll
    for (int seg = 0; seg < 3; ++seg) {
        const __bf16* Ap = (seg == 1) ? Alo : Ahi;
        const __bf16* Wp = (seg == 2) ? Wlo : Whi;
        for (int k0 = 0; k0 < K; k0 += BK) {
            __syncthreads();    // protect previous step's LDS reads
#pragma unroll
            for (int i = 0; i < BMt / 64; ++i) {
                const __bf16* src = Ap + (size_t)(bm + i * 64 + srow) * K + k0 + scol;
                __builtin_amdgcn_global_load_lds(
                    (const __attribute__((address_space(1))) void*)src,
                    (__attribute__((address_space(3))) void*)(As + i * 2048 + tid * 8),
                    16, 0, 0);
            }
#pragma unroll
            for (int i = 0; i < BNt / 64; ++i) {
                const __bf16* src = Wp + (size_t)(bn + i * 64 + srow) * K + k0 + scol;
                __builtin_amdgcn_global_load_lds(
                    (const __attribute__((address_space(1))) void*)src,
                    (__attribute__((address_space(3))) void*)(Ws + i * 2048 + tid * 8),
                    16, 0, 0);
            }
            __syncthreads();    // staging complete (vmcnt(0) drained by compiler)

            bf16x8 af[FR], wf[FC];
#pragma unroll
            for (int f = 0; f < FR; ++f)
                af[f] = *(const bf16x8*)&As[(arow + f * 16) * BK + kof];
#pragma unroll
            for (int f = 0; f < FC; ++f)
                wf[f] = *(const bf16x8*)&Ws[(brow + f * 16) * BK + kof];
#pragma unroll
            for (int i = 0; i < FR; ++i)
#pragma unroll
                for (int j = 0; j < FC; ++j)
                    acc[i][j] = __builtin_amdgcn_mfma_f32_16x16x32_bf16(
                        af[i], wf[j], acc[i][j], 0, 0, 0);
        }
    }

    // epilogue: C/D frag mapping col=lane&15, row=(lane>>4)*4+reg  [m89]
    const int rbase = bm + wr * (BMt / 2) + (lane >> 4) * 4;
    const int cbase = bn + wc * (BNt / 2) + (lane & 15);
#pragma unroll
    for (int i = 0; i < FR; ++i) {
#pragma unroll
        for (int j = 0; j < FC; ++j) {
#pragma unroll
            for (int r = 0; r < 4; ++r) {
                int row = rbase + i * 16 + r;
                int col = cbase + j * 16;
                if (col < N) {
                    float v = acc[i][j][r];
                    if (EPI == 1) v = 1.f / (1.f + __expf(-(v + bias[col])));
                    if (EPI == 2) v = v + resid[(size_t)row * N + col];
                    C[(size_t)row * N + col] = v;
                }
            }
        }
    }
}

// ---------------------------------------------------------------------------
// FP32 fallback GEMM (known-good from round 1) — used only if ws too small.
// ---------------------------------------------------------------------------
#define BM 128
#define BN 128
#define BKF 16

template <int EPI>
__global__ __launch_bounds__(256)
void gemm_wt(const float* __restrict__ A, const float* __restrict__ W,
             const float* __restrict__ bias, const float* __restrict__ resid,
             float* __restrict__ C, int M, int N, int K) {
    __shared__ float As[BKF][BM + 4];
    __shared__ float Wsh[BKF][BN + 4];
    const int tid = threadIdx.x;
    const int bm = blockIdx.y * BM;
    const int bn = blockIdx.x * BN;
    const int tx = tid & 15, ty = tid >> 4;
    const int lrow = tid >> 1;
    const int lk   = (tid & 1) * 8;
    float acc[8][8];
#pragma unroll
    for (int i = 0; i < 8; ++i)
#pragma unroll
        for (int j = 0; j < 8; ++j) acc[i][j] = 0.f;
    for (int k0 = 0; k0 < K; k0 += BKF) {
        const float* ap = A + (size_t)(bm + lrow) * K + k0 + lk;
        float4 av0 = *(const float4*)ap;
        float4 av1 = *(const float4*)(ap + 4);
        float4 wv0 = {0, 0, 0, 0}, wv1 = {0, 0, 0, 0};
        int wrow = bn + lrow;
        if (wrow < N) {
            const float* wp = W + (size_t)wrow * K + k0 + lk;
            wv0 = *(const float4*)wp;
            wv1 = *(const float4*)(wp + 4);
        }
        __syncthreads();
        As[lk + 0][lrow] = av0.x; As[lk + 1][lrow] = av0.y;
        As[lk + 2][lrow] = av0.z; As[lk + 3][lrow] = av0.w;
        As[lk + 4][lrow] = av1.x; As[lk + 5][lrow] = av1.y;
        As[lk + 6][lrow] = av1.z; As[lk + 7][lrow] = av1.w;
        Wsh[lk + 0][lrow] = wv0.x; Wsh[lk + 1][lrow] = wv0.y;
        Wsh[lk + 2][lrow] = wv0.z; Wsh[lk + 3][lrow] = wv0.w;
        Wsh[lk + 4][lrow] = wv1.x; Wsh[lk + 5][lrow] = wv1.y;
        Wsh[lk + 6][lrow] = wv1.z; Wsh[lk + 7][lrow] = wv1.w;
        __syncthreads();
#pragma unroll
        for (int k = 0; k < BKF; ++k) {
            float4 a0 = *(const float4*)&As[k][ty * 8];
            float4 a1 = *(const float4*)&As[k][ty * 8 + 4];
            float4 w0 = *(const float4*)&Wsh[k][tx * 8];
            float4 w1 = *(const float4*)&Wsh[k][tx * 8 + 4];
            float av[8] = {a0.x, a0.y, a0.z, a0.w, a1.x, a1.y, a1.z, a1.w};
            float wv[8] = {w0.x, w0.y, w0.z, w0.w, w1.x, w1.y, w1.z, w1.w};
#pragma unroll
            for (int i = 0; i < 8; ++i)
#pragma unroll
                for (int j = 0; j < 8; ++j)
                    acc[i][j] = fmaf(av[i], wv[j], acc[i][j]);
        }
    }
#pragma unroll
    for (int i = 0; i < 8; ++i) {
        int row = bm + ty * 8 + i;
#pragma unroll
        for (int j = 0; j < 8; ++j) {
            int col = bn + tx * 8 + j;
            if (col < N) {
                float v = acc[i][j];
                if (EPI == 1) v = 1.f / (1.f + expf(-(v + bias[col])));
                if (EPI == 2) v = v + resid[(size_t)row * N + col];
                C[(size_t)row * N + col] = v;
            }
        }
    }
}

// ---------------------------------------------------------------------------
// Host launcher
// ---------------------------------------------------------------------------
extern "C" void kernel_launch(void* const* d_in, const int* in_sizes, int n_in,
                              void* d_out, int out_size, void* d_ws, size_t ws_size,
                              hipStream_t stream) {
    (void)in_sizes; (void)n_in; (void)out_size;
    const int*   tokens  = (const int*)  d_in[0];
    const float* emb     = (const float*)d_in[1];
    const float* ln_g    = (const float*)d_in[2];
    const float* ln_b    = (const float*)d_in[3];
    const float* in_w    = (const float*)d_in[4];
    const float* conv_w  = (const float*)d_in[5];
    const float* conv_b  = (const float*)d_in[6];
    const float* dt_w    = (const float*)d_in[7];
    const float* dt_b    = (const float*)d_in[8];
    const float* A_log   = (const float*)d_in[9];
    const float* D_param = (const float*)d_in[10];
    const float* out_w   = (const float*)d_in[11];
    const float* lnf_g   = (const float*)d_in[12];
    const float* lnf_b   = (const float*)d_in[13];
    const float* head_w  = (const float*)d_in[14];
    float* out = (float*)d_out;

    // ---- workspace carve ----
    char* base = (char*)d_ws;
    char* p = base;
    auto alloc = [&](size_t bytes) -> char* {
        char* r = p;
        p += (bytes + 255) & ~(size_t)255;
        return r;
    };
    float* x  = (float*)alloc((size_t)BLD * 4);
    float* xn = (float*)alloc((size_t)BLD * 4);
    float* xr = (float*)alloc((size_t)2 * BLD * 4);
    float* xc = (float*)alloc((size_t)BLD * 4);
    float* dt = (float*)alloc((size_t)BLD * 4);
    float* y  = xn;  // xn dead after in_proj
    size_t fb_need = (size_t)(p - base);

    __bf16* a_hi = (__bf16*)alloc((size_t)BLD * 2);
    __bf16* a_lo = (__bf16*)alloc((size_t)BLD * 2);
    const size_t INW = (size_t)NL_ * 2 * D_ * D_;   // 4*1536*768
    const size_t SQW = (size_t)NL_ * D_ * D_;       // 4*768*768
    const size_t HW  = (size_t)VPAD * D_;           // padded head
    __bf16* inw_hi  = (__bf16*)alloc(INW * 2);
    __bf16* inw_lo  = (__bf16*)alloc(INW * 2);
    __bf16* dtw_hi  = (__bf16*)alloc(SQW * 2);
    __bf16* dtw_lo  = (__bf16*)alloc(SQW * 2);
    __bf16* outw_hi = (__bf16*)alloc(SQW * 2);
    __bf16* outw_lo = (__bf16*)alloc(SQW * 2);
    __bf16* hw_hi   = (__bf16*)alloc(HW * 2);
    __bf16* hw_lo   = (__bf16*)alloc(HW * 2);
    size_t fast_need = (size_t)(p - base);

    const bool fast = ws_size >= fast_need && fb_need <= ws_size;

    emb_kernel<<<(BLD + 255) / 256, 256, 0, stream>>>(tokens, emb, x);

    if (fast) {
        // weight splits (once per launch)
        int n4;
        n4 = (int)(INW / 4);
        split4_kernel<<<(n4 + 255) / 256, 256, 0, stream>>>(in_w, inw_hi, inw_lo, n4, n4);
        n4 = (int)(SQW / 4);
        split4_kernel<<<(n4 + 255) / 256, 256, 0, stream>>>(dt_w, dtw_hi, dtw_lo, n4, n4);
        split4_kernel<<<(n4 + 255) / 256, 256, 0, stream>>>(out_w, outw_hi, outw_lo, n4, n4);
        {
            int hn4 = (int)((size_t)V_ * D_ / 4), hp4 = (int)(HW / 4);
            split4_kernel<<<(hp4 + 255) / 256, 256, 0, stream>>>(head_w, hw_hi, hw_lo, hn4, hp4);
        }
        const int an4 = BLD / 4;

        for (int l = 0; l < NL_; ++l) {
            const float* lg = ln_g + (size_t)l * D_;
            const float* lb = ln_b + (size_t)l * D_;
            const float* cw = conv_w + (size_t)l * D_ * 3;
            const float* cb = conv_b + (size_t)l * D_;
            const float* db = dt_b + (size_t)l * D_;
            const float* al = A_log + (size_t)l * D_ * S_;
            const float* dp = D_param + (size_t)l * D_;
            const __bf16* iwh = inw_hi + (size_t)l * 2 * D_ * D_;
            const __bf16* iwl = inw_lo + (size_t)l * 2 * D_ * D_;
            const __bf16* dwh = dtw_hi + (size_t)l * D_ * D_;
            const __bf16* dwl = dtw_lo + (size_t)l * D_ * D_;
            const __bf16* owh = outw_hi + (size_t)l * D_ * D_;
            const __bf16* owl = outw_lo + (size_t)l * D_ * D_;

            ln_kernel<<<ROWS, 256, 0, stream>>>(x, lg, lb, xn);
            split4_kernel<<<(an4 + 255) / 256, 256, 0, stream>>>(xn, a_hi, a_lo, an4, an4);
            gemm_mfma<64, 128, 0><<<dim3((2 * D_) / 128, ROWS / 64), 256, 0, stream>>>(
                a_hi, a_lo, iwh, iwl, nullptr, nullptr, xr, ROWS, 2 * D_, D_);
            conv_silu_kernel<<<(BLD + 255) / 256, 256, 0, stream>>>(xr, cw, cb, xc);
            split4_kernel<<<(an4 + 255) / 256, 256, 0, stream>>>(xc, a_hi, a_lo, an4, an4);
            gemm_mfma<64, 128, 1><<<dim3(D_ / 128, ROWS / 64), 256, 0, stream>>>(
                a_hi, a_lo, dwh, dwl, db, nullptr, dt, ROWS, D_, D_);
            scan_kernel<<<(B_ * D_ * S_) / 256, 256, 0, stream>>>(dt, xc, xr, al, dp, y);
            split4_kernel<<<(an4 + 255) / 256, 256, 0, stream>>>(y, a_hi, a_lo, an4, an4);
            gemm_mfma<64, 128, 2><<<dim3(D_ / 128, ROWS / 64), 256, 0, stream>>>(
                a_hi, a_lo, owh, owl, nullptr, x, x, ROWS, D_, D_);
        }

        ln_kernel<<<ROWS, 256, 0, stream>>>(x, lnf_g, lnf_b, xn);
        split4_kernel<<<(an4 + 255) / 256, 256, 0, stream>>>(xn, a_hi, a_lo, an4, an4);
        gemm_mfma<128, 128, 0><<<dim3(VPAD / 128, ROWS / 128), 256, 0, stream>>>(
            a_hi, a_lo, hw_hi, hw_lo, nullptr, nullptr, out, ROWS, V_, D_);
    } else {
        // fp32 fallback (round-1 path)
        for (int l = 0; l < NL_; ++l) {
            const float* lg = ln_g + (size_t)l * D_;
            const float* lb = ln_b + (size_t)l * D_;
            const float* iw = in_w + (size_t)l * 2 * D_ * D_;
            const float* cw = conv_w + (size_t)l * D_ * 3;
            const float* cb = conv_b + (size_t)l * D_;
            const float* dw = dt_w + (size_t)l * D_ * D_;
            const float* db = dt_b + (size_t)l * D_;
            const float* al = A_log + (size_t)l * D_ * S_;
            const float* dp = D_param + (size_t)l * D_;
            const float* ow = out_w + (size_t)l * D_ * D_;
            ln_kernel<<<ROWS, 256, 0, stream>>>(x, lg, lb, xn);
            gemm_wt<0><<<dim3((2 * D_) / BN, ROWS / BM), 256, 0, stream>>>(
                xn, iw, nullptr, nullptr, xr, ROWS, 2 * D_, D_);
            conv_silu_kernel<<<(BLD + 255) / 256, 256, 0, stream>>>(xr, cw, cb, xc);
            gemm_wt<1><<<dim3(D_ / BN, ROWS / BM), 256, 0, stream>>>(
                xc, dw, db, nullptr, dt, ROWS, D_, D_);
            scan_kernel<<<(B_ * D_ * S_) / 256, 256, 0, stream>>>(dt, xc, xr, al, dp, y);
            gemm_wt<2><<<dim3(D_ / BN, ROWS / BM), 256, 0, stream>>>(
                y, ow, nullptr, x, x, ROWS, D_, D_);
        }
        ln_kernel<<<ROWS, 256, 0, stream>>>(x, lnf_g, lnf_b, xn);
        gemm_wt<0><<<dim3((V_ + BN - 1) / BN, ROWS / BM), 256, 0, stream>>>(
            xn, head_w, nullptr, nullptr, out, ROWS, V_, D_);
    }
}

// Round 5
// 1788.222 us; speedup vs baseline: 2.1444x; 1.1303x over previous
//
#include <hip/hip_runtime.h>
#include <math.h>

// Problem constants (match reference)
#define V_  50257
#define D_  768
#define S_  16
#define NL_ 4
#define B_  2
#define L_  512
#define EPS_ 1e-5f

static constexpr int BLD  = B_ * L_ * D_;     // 786432
static constexpr int ROWS = B_ * L_;          // 1024
static constexpr int VPAD = 50304;            // V_ rounded up to 128

typedef __bf16 bf16x8 __attribute__((ext_vector_type(8)));
typedef __bf16 bf16x4 __attribute__((ext_vector_type(4)));
typedef float  f32x4  __attribute__((ext_vector_type(4)));

// ---------------------------------------------------------------------------
// Embedding gather
// ---------------------------------------------------------------------------
__global__ __launch_bounds__(256)
void emb_kernel(const int* __restrict__ tok, const float* __restrict__ emb,
                float* __restrict__ x) {
    int i = blockIdx.x * 256 + threadIdx.x;
    if (i >= BLD) return;
    int d  = i % D_;
    int bl = i / D_;
    x[i] = emb[(size_t)tok[bl] * D_ + d];
}

// ---------------------------------------------------------------------------
// LayerNorm + hi/lo bf16 split epilogue (feeds gemm3 directly)
// ---------------------------------------------------------------------------
__global__ __launch_bounds__(256)
void ln_split_kernel(const float* __restrict__ x, const float* __restrict__ g,
                     const float* __restrict__ b, __bf16* __restrict__ hi,
                     __bf16* __restrict__ lo) {
    int row = blockIdx.x;
    const float* xr = x + (size_t)row * D_;
    int t = threadIdx.x;
    float v0 = xr[t], v1 = xr[t + 256], v2 = xr[t + 512];
    float s1 = v0 + v1 + v2;
    float s2 = v0 * v0 + v1 * v1 + v2 * v2;
    for (int off = 32; off > 0; off >>= 1) {
        s1 += __shfl_down(s1, off);
        s2 += __shfl_down(s2, off);
    }
    __shared__ float red[8];
    __shared__ float mv[2];
    int wave = t >> 6, lane = t & 63;
    if (lane == 0) { red[wave] = s1; red[4 + wave] = s2; }
    __syncthreads();
    if (t == 0) {
        float a = red[0] + red[1] + red[2] + red[3];
        float c = red[4] + red[5] + red[6] + red[7];
        float mean = a / (float)D_;
        float var  = c / (float)D_ - mean * mean;
        mv[0] = mean;
        mv[1] = 1.f / sqrtf(var + EPS_);
    }
    __syncthreads();
    float mean = mv[0], inv = mv[1];
    size_t o = (size_t)row * D_;
#pragma unroll
    for (int q = 0; q < 3; ++q) {
        int c = t + q * 256;
        float v = (q == 0 ? v0 : q == 1 ? v1 : v2);
        float n = (v - mean) * inv * g[c] + b[c];
        __bf16 h = (__bf16)n;
        hi[o + c] = h;
        lo[o + c] = (__bf16)(n - (float)h);
    }
}

// Plain LN (fallback path only)
__global__ __launch_bounds__(256)
void ln_kernel(const float* __restrict__ x, const float* __restrict__ g,
               const float* __restrict__ b, float* __restrict__ o) {
    int row = blockIdx.x;
    const float* xr = x + (size_t)row * D_;
    int t = threadIdx.x;
    float v0 = xr[t], v1 = xr[t + 256], v2 = xr[t + 512];
    float s1 = v0 + v1 + v2;
    float s2 = v0 * v0 + v1 * v1 + v2 * v2;
    for (int off = 32; off > 0; off >>= 1) {
        s1 += __shfl_down(s1, off);
        s2 += __shfl_down(s2, off);
    }
    __shared__ float red[8];
    __shared__ float mv[2];
    int wave = t >> 6, lane = t & 63;
    if (lane == 0) { red[wave] = s1; red[4 + wave] = s2; }
    __syncthreads();
    if (t == 0) {
        float a = red[0] + red[1] + red[2] + red[3];
        float c = red[4] + red[5] + red[6] + red[7];
        float mean = a / (float)D_;
        float var  = c / (float)D_ - mean * mean;
        mv[0] = mean;
        mv[1] = 1.f / sqrtf(var + EPS_);
    }
    __syncthreads();
    float mean = mv[0], inv = mv[1];
    float* orow = o + (size_t)row * D_;
    orow[t]       = (v0 - mean) * inv * g[t]       + b[t];
    orow[t + 256] = (v1 - mean) * inv * g[t + 256] + b[t + 256];
    orow[t + 512] = (v2 - mean) * inv * g[t + 512] + b[t + 512];
}

// ---------------------------------------------------------------------------
// Depthwise conv (w=3) + bias + SiLU; writes fp32 xc AND hi/lo split.
// ---------------------------------------------------------------------------
__global__ __launch_bounds__(256)
void conv_silu_split_kernel(const float* __restrict__ xr, const float* __restrict__ cw,
                            const float* __restrict__ cb, float* __restrict__ xc,
                            __bf16* __restrict__ hi, __bf16* __restrict__ lo) {
    int i = blockIdx.x * 256 + threadIdx.x;
    if (i >= BLD) return;
    int d  = i % D_;
    int bl = i / D_;
    int l  = bl % L_;
    const size_t stride = 2 * D_;
    float xm = (l > 0)      ? xr[(size_t)(bl - 1) * stride + d] : 0.f;
    float x0 =                xr[(size_t)bl * stride + d];
    float xp = (l < L_ - 1) ? xr[(size_t)(bl + 1) * stride + d] : 0.f;
    float v = xm * cw[d * 3 + 0] + x0 * cw[d * 3 + 1] + xp * cw[d * 3 + 2] + cb[d];
    float s = v / (1.f + __expf(-v));
    xc[i] = s;
    __bf16 h = (__bf16)s;
    hi[i] = h;
    lo[i] = (__bf16)(s - (float)h);
}

__global__ __launch_bounds__(256)
void conv_silu_kernel(const float* __restrict__ xr, const float* __restrict__ cw,
                      const float* __restrict__ cb, float* __restrict__ xc) {
    int i = blockIdx.x * 256 + threadIdx.x;
    if (i >= BLD) return;
    int d  = i % D_;
    int bl = i / D_;
    int l  = bl % L_;
    const size_t stride = 2 * D_;
    float xm = (l > 0)      ? xr[(size_t)(bl - 1) * stride + d] : 0.f;
    float x0 =                xr[(size_t)bl * stride + d];
    float xp = (l < L_ - 1) ? xr[(size_t)(bl + 1) * stride + d] : 0.f;
    float v = xm * cw[d * 3 + 0] + x0 * cw[d * 3 + 1] + xp * cw[d * 3 + 2] + cb[d];
    xc[i] = v / (1.f + __expf(-v));
}

// ---------------------------------------------------------------------------
// Selective scan; s==0 lane writes y hi/lo split directly.
// ---------------------------------------------------------------------------
template <int SPLIT>
__global__ __launch_bounds__(256)
void scan_kernel(const float* __restrict__ dt, const float* __restrict__ xc,
                 const float* __restrict__ xr, const float* __restrict__ A_log,
                 const float* __restrict__ Dp, float* __restrict__ y,
                 __bf16* __restrict__ yh, __bf16* __restrict__ yl) {
    int t = blockIdx.x * 256 + threadIdx.x;
    int s = t & (S_ - 1);
    int d = (t >> 4) % D_;
    int b = t / (D_ * S_);
    float a  = -__expf(A_log[d * S_ + s]);
    float Dd = Dp[d];
    const float* dtp = dt + (size_t)b * L_ * D_ + d;
    const float* xcp = xc + (size_t)b * L_ * D_ + d;
    const float* rsp = xr + (size_t)b * L_ * 2 * D_ + D_ + d;
    size_t ybase = (size_t)b * L_ * D_ + d;
    float h = 0.f;
    float dtv = dtp[0], xcv = xcp[0], rv = rsp[0];
    for (int l = 0; l < L_; ++l) {
        float dtn = 0.f, xcn = 0.f, rn = 0.f;
        if (l + 1 < L_) {
            dtn = dtp[(size_t)(l + 1) * D_];
            xcn = xcp[(size_t)(l + 1) * D_];
            rn  = rsp[(size_t)(l + 1) * 2 * D_];
        }
        h = h * __expf(a * dtv) + xcv;
        float ys = h;
        ys += __shfl_xor(ys, 1, 16);
        ys += __shfl_xor(ys, 2, 16);
        ys += __shfl_xor(ys, 4, 16);
        ys += __shfl_xor(ys, 8, 16);
        if (s == 0) {
            float sil = rv / (1.f + __expf(-rv));
            float val = ys * Dd * sil;
            if (SPLIT) {
                __bf16 hh = (__bf16)val;
                yh[ybase + (size_t)l * D_] = hh;
                yl[ybase + (size_t)l * D_] = (__bf16)(val - (float)hh);
            } else {
                y[ybase + (size_t)l * D_] = val;
            }
        }
        dtv = dtn; xcv = xcn; rv = rn;
    }
}

// ---------------------------------------------------------------------------
// fp32 -> (hi, lo) bf16 split for weights. i >= n4 -> zero fill (pad).
// ---------------------------------------------------------------------------
__global__ __launch_bounds__(256)
void split4_kernel(const float* __restrict__ x, __bf16* __restrict__ hi,
                   __bf16* __restrict__ lo, int n4, int npad4) {
    int i = blockIdx.x * 256 + threadIdx.x;
    if (i >= npad4) return;
    float4 v = {0.f, 0.f, 0.f, 0.f};
    if (i < n4) v = ((const float4*)x)[i];
    bf16x4 h, l;
    h[0] = (__bf16)v.x; h[1] = (__bf16)v.y; h[2] = (__bf16)v.z; h[3] = (__bf16)v.w;
    l[0] = (__bf16)(v.x - (float)h[0]);
    l[1] = (__bf16)(v.y - (float)h[1]);
    l[2] = (__bf16)(v.z - (float)h[2]);
    l[3] = (__bf16)(v.w - (float)h[3]);
    *(bf16x4*)&hi[(size_t)i * 4] = h;
    *(bf16x4*)&lo[(size_t)i * 4] = l;
}

// ---------------------------------------------------------------------------
// Single-pass split-bf16 MFMA GEMM: C = A @ W^T with
// acc += Ahi*Whi + Alo*Whi + Ahi*Wlo computed per K-step from one staging.
// Grid: blockIdx.x = M-blocks (fast-varying -> same-W blocks concurrent),
//       blockIdx.y = N-blocks.
// 256 threads = 4 waves (2x2). EPI: 0 plain, 1 sigmoid(v+bias), 2 v+resid.
// ---------------------------------------------------------------------------
template <int BMt, int BNt, int EPI>
__global__ __launch_bounds__(256)
void gemm3(const __bf16* __restrict__ Ahi, const __bf16* __restrict__ Alo,
           const __bf16* __restrict__ Whi, const __bf16* __restrict__ Wlo,
           const float* __restrict__ bias, const float* __restrict__ resid,
           float* __restrict__ C, int N, int K) {
    constexpr int BK = 32;
    constexpr int FR = BMt / 32;
    constexpr int FC = BNt / 32;
    __shared__ __bf16 Ah[BMt * BK];
    __shared__ __bf16 Al[BMt * BK];
    __shared__ __bf16 Wh[BNt * BK];
    __shared__ __bf16 Wl[BNt * BK];
    const int tid  = threadIdx.x;
    const int lane = tid & 63;
    const int wv   = tid >> 6;
    const int wr   = wv >> 1, wc = wv & 1;
    const int bm   = blockIdx.x * BMt;   // M fast-varying
    const int bn   = blockIdx.y * BNt;

    const int srow = tid >> 2;           // 0..63
    const int scol = (tid & 3) * 8;

    f32x4 acc[FR][FC] = {};

    const int arow = wr * (BMt / 2) + (lane & 15);
    const int brow = wc * (BNt / 2) + (lane & 15);
    const int kof  = (lane >> 4) * 8;

    for (int k0 = 0; k0 < K; k0 += BK) {
        __syncthreads();    // protect previous step's LDS reads
#pragma unroll
        for (int i = 0; i < BMt / 64; ++i) {
            size_t go = (size_t)(bm + i * 64 + srow) * K + k0 + scol;
            __builtin_amdgcn_global_load_lds(
                (const __attribute__((address_space(1))) void*)(Ahi + go),
                (__attribute__((address_space(3))) void*)(Ah + i * 2048 + tid * 8),
                16, 0, 0);
            __builtin_amdgcn_global_load_lds(
                (const __attribute__((address_space(1))) void*)(Alo + go),
                (__attribute__((address_space(3))) void*)(Al + i * 2048 + tid * 8),
                16, 0, 0);
        }
#pragma unroll
        for (int i = 0; i < BNt / 64; ++i) {
            size_t go = (size_t)(bn + i * 64 + srow) * K + k0 + scol;
            __builtin_amdgcn_global_load_lds(
                (const __attribute__((address_space(1))) void*)(Whi + go),
                (__attribute__((address_space(3))) void*)(Wh + i * 2048 + tid * 8),
                16, 0, 0);
            __builtin_amdgcn_global_load_lds(
                (const __attribute__((address_space(1))) void*)(Wlo + go),
                (__attribute__((address_space(3))) void*)(Wl + i * 2048 + tid * 8),
                16, 0, 0);
        }
        __syncthreads();

        bf16x8 afh[FR], afl[FR], wfh[FC], wfl[FC];
#pragma unroll
        for (int f = 0; f < FR; ++f) {
            afh[f] = *(const bf16x8*)&Ah[(arow + f * 16) * BK + kof];
            afl[f] = *(const bf16x8*)&Al[(arow + f * 16) * BK + kof];
        }
#pragma unroll
        for (int f = 0; f < FC; ++f) {
            wfh[f] = *(const bf16x8*)&Wh[(brow + f * 16) * BK + kof];
            wfl[f] = *(const bf16x8*)&Wl[(brow + f * 16) * BK + kof];
        }
#pragma unroll
        for (int i = 0; i < FR; ++i)
#pragma unroll
            for (int j = 0; j < FC; ++j) {
                acc[i][j] = __builtin_amdgcn_mfma_f32_16x16x32_bf16(
                    afh[i], wfh[j], acc[i][j], 0, 0, 0);
                acc[i][j] = __builtin_amdgcn_mfma_f32_16x16x32_bf16(
                    afl[i], wfh[j], acc[i][j], 0, 0, 0);
                acc[i][j] = __builtin_amdgcn_mfma_f32_16x16x32_bf16(
                    afh[i], wfl[j], acc[i][j], 0, 0, 0);
            }
    }

    // epilogue: C/D frag mapping col=lane&15, row=(lane>>4)*4+reg  [m89]
    const int rbase = bm + wr * (BMt / 2) + (lane >> 4) * 4;
    const int cbase = bn + wc * (BNt / 2) + (lane & 15);
#pragma unroll
    for (int i = 0; i < FR; ++i) {
#pragma unroll
        for (int j = 0; j < FC; ++j) {
#pragma unroll
            for (int r = 0; r < 4; ++r) {
                int row = rbase + i * 16 + r;
                int col = cbase + j * 16;
                if (col < N) {
                    float v = acc[i][j][r];
                    if (EPI == 1) v = 1.f / (1.f + __expf(-(v + bias[col])));
                    if (EPI == 2) v = v + resid[(size_t)row * N + col];
                    C[(size_t)row * N + col] = v;
                }
            }
        }
    }
}

// ---------------------------------------------------------------------------
// FP32 fallback GEMM (known-good from round 1) — used only if ws too small.
// ---------------------------------------------------------------------------
#define BM 128
#define BN 128
#define BKF 16

template <int EPI>
__global__ __launch_bounds__(256)
void gemm_wt(const float* __restrict__ A, const float* __restrict__ W,
             const float* __restrict__ bias, const float* __restrict__ resid,
             float* __restrict__ C, int M, int N, int K) {
    __shared__ float As[BKF][BM + 4];
    __shared__ float Wsh[BKF][BN + 4];
    const int tid = threadIdx.x;
    const int bm = blockIdx.y * BM;
    const int bn = blockIdx.x * BN;
    const int tx = tid & 15, ty = tid >> 4;
    const int lrow = tid >> 1;
    const int lk   = (tid & 1) * 8;
    float acc[8][8];
#pragma unroll
    for (int i = 0; i < 8; ++i)
#pragma unroll
        for (int j = 0; j < 8; ++j) acc[i][j] = 0.f;
    for (int k0 = 0; k0 < K; k0 += BKF) {
        const float* ap = A + (size_t)(bm + lrow) * K + k0 + lk;
        float4 av0 = *(const float4*)ap;
        float4 av1 = *(const float4*)(ap + 4);
        float4 wv0 = {0, 0, 0, 0}, wv1 = {0, 0, 0, 0};
        int wrow = bn + lrow;
        if (wrow < N) {
            const float* wp = W + (size_t)wrow * K + k0 + lk;
            wv0 = *(const float4*)wp;
            wv1 = *(const float4*)(wp + 4);
        }
        __syncthreads();
        As[lk + 0][lrow] = av0.x; As[lk + 1][lrow] = av0.y;
        As[lk + 2][lrow] = av0.z; As[lk + 3][lrow] = av0.w;
        As[lk + 4][lrow] = av1.x; As[lk + 5][lrow] = av1.y;
        As[lk + 6][lrow] = av1.z; As[lk + 7][lrow] = av1.w;
        Wsh[lk + 0][lrow] = wv0.x; Wsh[lk + 1][lrow] = wv0.y;
        Wsh[lk + 2][lrow] = wv0.z; Wsh[lk + 3][lrow] = wv0.w;
        Wsh[lk + 4][lrow] = wv1.x; Wsh[lk + 5][lrow] = wv1.y;
        Wsh[lk + 6][lrow] = wv1.z; Wsh[lk + 7][lrow] = wv1.w;
        __syncthreads();
#pragma unroll
        for (int k = 0; k < BKF; ++k) {
            float4 a0 = *(const float4*)&As[k][ty * 8];
            float4 a1 = *(const float4*)&As[k][ty * 8 + 4];
            float4 w0 = *(const float4*)&Wsh[k][tx * 8];
            float4 w1 = *(const float4*)&Wsh[k][tx * 8 + 4];
            float av[8] = {a0.x, a0.y, a0.z, a0.w, a1.x, a1.y, a1.z, a1.w};
            float wv[8] = {w0.x, w0.y, w0.z, w0.w, w1.x, w1.y, w1.z, w1.w};
#pragma unroll
            for (int i = 0; i < 8; ++i)
#pragma unroll
                for (int j = 0; j < 8; ++j)
                    acc[i][j] = fmaf(av[i], wv[j], acc[i][j]);
        }
    }
#pragma unroll
    for (int i = 0; i < 8; ++i) {
        int row = bm + ty * 8 + i;
#pragma unroll
        for (int j = 0; j < 8; ++j) {
            int col = bn + tx * 8 + j;
            if (col < N) {
                float v = acc[i][j];
                if (EPI == 1) v = 1.f / (1.f + expf(-(v + bias[col])));
                if (EPI == 2) v = v + resid[(size_t)row * N + col];
                C[(size_t)row * N + col] = v;
            }
        }
    }
}

// ---------------------------------------------------------------------------
// Host launcher
// ---------------------------------------------------------------------------
extern "C" void kernel_launch(void* const* d_in, const int* in_sizes, int n_in,
                              void* d_out, int out_size, void* d_ws, size_t ws_size,
                              hipStream_t stream) {
    (void)in_sizes; (void)n_in; (void)out_size;
    const int*   tokens  = (const int*)  d_in[0];
    const float* emb     = (const float*)d_in[1];
    const float* ln_g    = (const float*)d_in[2];
    const float* ln_b    = (const float*)d_in[3];
    const float* in_w    = (const float*)d_in[4];
    const float* conv_w  = (const float*)d_in[5];
    const float* conv_b  = (const float*)d_in[6];
    const float* dt_w    = (const float*)d_in[7];
    const float* dt_b    = (const float*)d_in[8];
    const float* A_log   = (const float*)d_in[9];
    const float* D_param = (const float*)d_in[10];
    const float* out_w   = (const float*)d_in[11];
    const float* lnf_g   = (const float*)d_in[12];
    const float* lnf_b   = (const float*)d_in[13];
    const float* head_w  = (const float*)d_in[14];
    float* out = (float*)d_out;

    // ---- workspace carve ----
    char* base = (char*)d_ws;
    char* p = base;
    auto alloc = [&](size_t bytes) -> char* {
        char* r = p;
        p += (bytes + 255) & ~(size_t)255;
        return r;
    };
    float* x  = (float*)alloc((size_t)BLD * 4);
    float* xn = (float*)alloc((size_t)BLD * 4);   // fallback only
    float* xr = (float*)alloc((size_t)2 * BLD * 4);
    float* xc = (float*)alloc((size_t)BLD * 4);
    float* dt = (float*)alloc((size_t)BLD * 4);
    float* y  = xn;  // fallback alias
    size_t fb_need = (size_t)(p - base);

    __bf16* a_hi = (__bf16*)alloc((size_t)BLD * 2);
    __bf16* a_lo = (__bf16*)alloc((size_t)BLD * 2);
    const size_t INW = (size_t)NL_ * 2 * D_ * D_;
    const size_t SQW = (size_t)NL_ * D_ * D_;
    const size_t HW  = (size_t)VPAD * D_;
    __bf16* inw_hi  = (__bf16*)alloc(INW * 2);
    __bf16* inw_lo  = (__bf16*)alloc(INW * 2);
    __bf16* dtw_hi  = (__bf16*)alloc(SQW * 2);
    __bf16* dtw_lo  = (__bf16*)alloc(SQW * 2);
    __bf16* outw_hi = (__bf16*)alloc(SQW * 2);
    __bf16* outw_lo = (__bf16*)alloc(SQW * 2);
    __bf16* hw_hi   = (__bf16*)alloc(HW * 2);
    __bf16* hw_lo   = (__bf16*)alloc(HW * 2);
    size_t fast_need = (size_t)(p - base);

    const bool fast = ws_size >= fast_need && fb_need <= ws_size;

    emb_kernel<<<(BLD + 255) / 256, 256, 0, stream>>>(tokens, emb, x);

    if (fast) {
        // weight splits (inputs restored every call -> must re-split)
        int n4;
        n4 = (int)(INW / 4);
        split4_kernel<<<(n4 + 255) / 256, 256, 0, stream>>>(in_w, inw_hi, inw_lo, n4, n4);
        n4 = (int)(SQW / 4);
        split4_kernel<<<(n4 + 255) / 256, 256, 0, stream>>>(dt_w, dtw_hi, dtw_lo, n4, n4);
        split4_kernel<<<(n4 + 255) / 256, 256, 0, stream>>>(out_w, outw_hi, outw_lo, n4, n4);
        {
            int hn4 = (int)((size_t)V_ * D_ / 4), hp4 = (int)(HW / 4);
            split4_kernel<<<(hp4 + 255) / 256, 256, 0, stream>>>(head_w, hw_hi, hw_lo, hn4, hp4);
        }

        for (int l = 0; l < NL_; ++l) {
            const float* lg = ln_g + (size_t)l * D_;
            const float* lb = ln_b + (size_t)l * D_;
            const float* cw = conv_w + (size_t)l * D_ * 3;
            const float* cb = conv_b + (size_t)l * D_;
            const float* db = dt_b + (size_t)l * D_;
            const float* al = A_log + (size_t)l * D_ * S_;
            const float* dp = D_param + (size_t)l * D_;
            const __bf16* iwh = inw_hi + (size_t)l * 2 * D_ * D_;
            const __bf16* iwl = inw_lo + (size_t)l * 2 * D_ * D_;
            const __bf16* dwh = dtw_hi + (size_t)l * D_ * D_;
            const __bf16* dwl = dtw_lo + (size_t)l * D_ * D_;
            const __bf16* owh = outw_hi + (size_t)l * D_ * D_;
            const __bf16* owl = outw_lo + (size_t)l * D_ * D_;

            ln_split_kernel<<<ROWS, 256, 0, stream>>>(x, lg, lb, a_hi, a_lo);
            gemm3<64, 128, 0><<<dim3(ROWS / 64, (2 * D_) / 128), 256, 0, stream>>>(
                a_hi, a_lo, iwh, iwl, nullptr, nullptr, xr, 2 * D_, D_);
            conv_silu_split_kernel<<<(BLD + 255) / 256, 256, 0, stream>>>(
                xr, cw, cb, xc, a_hi, a_lo);
            gemm3<64, 128, 1><<<dim3(ROWS / 64, D_ / 128), 256, 0, stream>>>(
                a_hi, a_lo, dwh, dwl, db, nullptr, dt, D_, D_);
            scan_kernel<1><<<(B_ * D_ * S_) / 256, 256, 0, stream>>>(
                dt, xc, xr, al, dp, nullptr, a_hi, a_lo);
            gemm3<64, 128, 2><<<dim3(ROWS / 64, D_ / 128), 256, 0, stream>>>(
                a_hi, a_lo, owh, owl, nullptr, x, x, D_, D_);
        }

        ln_split_kernel<<<ROWS, 256, 0, stream>>>(x, lnf_g, lnf_b, a_hi, a_lo);
        gemm3<128, 128, 0><<<dim3(ROWS / 128, VPAD / 128), 256, 0, stream>>>(
            a_hi, a_lo, hw_hi, hw_lo, nullptr, nullptr, out, V_, D_);
    } else {
        // fp32 fallback (round-1 path)
        for (int l = 0; l < NL_; ++l) {
            const float* lg = ln_g + (size_t)l * D_;
            const float* lb = ln_b + (size_t)l * D_;
            const float* iw = in_w + (size_t)l * 2 * D_ * D_;
            const float* cw = conv_w + (size_t)l * D_ * 3;
            const float* cb = conv_b + (size_t)l * D_;
            const float* dw = dt_w + (size_t)l * D_ * D_;
            const float* db = dt_b + (size_t)l * D_;
            const float* al = A_log + (size_t)l * D_ * S_;
            const float* dp = D_param + (size_t)l * D_;
            const float* ow = out_w + (size_t)l * D_ * D_;
            ln_kernel<<<ROWS, 256, 0, stream>>>(x, lg, lb, xn);
            gemm_wt<0><<<dim3((2 * D_) / BN, ROWS / BM), 256, 0, stream>>>(
                xn, iw, nullptr, nullptr, xr, ROWS, 2 * D_, D_);
            conv_silu_kernel<<<(BLD + 255) / 256, 256, 0, stream>>>(xr, cw, cb, xc);
            gemm_wt<1><<<dim3(D_ / BN, ROWS / BM), 256, 0, stream>>>(
                xc, dw, db, nullptr, dt, ROWS, D_, D_);
            scan_kernel<0><<<(B_ * D_ * S_) / 256, 256, 0, stream>>>(
                dt, xc, xr, al, dp, y, nullptr, nullptr);
            gemm_wt<2><<<dim3(D_ / BN, ROWS / BM), 256, 0, stream>>>(
                y, ow, nullptr, x, x, ROWS, D_, D_);
        }
        ln_kernel<<<ROWS, 256, 0, stream>>>(x, lnf_g, lnf_b, xn);
        gemm_wt<0><<<dim3((V_ + BN - 1) / BN, ROWS / BM), 256, 0, stream>>>(
            xn, head_w, nullptr, nullptr, out, ROWS, V_, D_);
    }
}

// Round 6
// 1272.637 us; speedup vs baseline: 3.0132x; 1.4051x over previous
//
#include <hip/hip_runtime.h>
#include <math.h>

// Problem constants (match reference)
#define V_  50257
#define D_  768
#define S_  16
#define NL_ 4
#define B_  2
#define L_  512
#define EPS_ 1e-5f

static constexpr int BLD  = B_ * L_ * D_;     // 786432
static constexpr int ROWS = B_ * L_;          // 1024
static constexpr int VPAD = 50304;            // V_ rounded up to 128

typedef __bf16 bf16x8 __attribute__((ext_vector_type(8)));
typedef __bf16 bf16x4 __attribute__((ext_vector_type(4)));
typedef float  f32x4  __attribute__((ext_vector_type(4)));

// ---------------------------------------------------------------------------
// Embedding gather
// ---------------------------------------------------------------------------
__global__ __launch_bounds__(256)
void emb_kernel(const int* __restrict__ tok, const float* __restrict__ emb,
                float* __restrict__ x) {
    int i = blockIdx.x * 256 + threadIdx.x;
    if (i >= BLD) return;
    int d  = i % D_;
    int bl = i / D_;
    x[i] = emb[(size_t)tok[bl] * D_ + d];
}

// ---------------------------------------------------------------------------
// LayerNorm + hi/lo bf16 split epilogue
// ---------------------------------------------------------------------------
__global__ __launch_bounds__(256)
void ln_split_kernel(const float* __restrict__ x, const float* __restrict__ g,
                     const float* __restrict__ b, __bf16* __restrict__ hi,
                     __bf16* __restrict__ lo) {
    int row = blockIdx.x;
    const float* xr = x + (size_t)row * D_;
    int t = threadIdx.x;
    float v0 = xr[t], v1 = xr[t + 256], v2 = xr[t + 512];
    float s1 = v0 + v1 + v2;
    float s2 = v0 * v0 + v1 * v1 + v2 * v2;
    for (int off = 32; off > 0; off >>= 1) {
        s1 += __shfl_down(s1, off);
        s2 += __shfl_down(s2, off);
    }
    __shared__ float red[8];
    __shared__ float mv[2];
    int wave = t >> 6, lane = t & 63;
    if (lane == 0) { red[wave] = s1; red[4 + wave] = s2; }
    __syncthreads();
    if (t == 0) {
        float a = red[0] + red[1] + red[2] + red[3];
        float c = red[4] + red[5] + red[6] + red[7];
        float mean = a / (float)D_;
        float var  = c / (float)D_ - mean * mean;
        mv[0] = mean;
        mv[1] = 1.f / sqrtf(var + EPS_);
    }
    __syncthreads();
    float mean = mv[0], inv = mv[1];
    size_t o = (size_t)row * D_;
#pragma unroll
    for (int q = 0; q < 3; ++q) {
        int c = t + q * 256;
        float v = (q == 0 ? v0 : q == 1 ? v1 : v2);
        float n = (v - mean) * inv * g[c] + b[c];
        __bf16 h = (__bf16)n;
        hi[o + c] = h;
        lo[o + c] = (__bf16)(n - (float)h);
    }
}

// Plain LN (fallback path only)
__global__ __launch_bounds__(256)
void ln_kernel(const float* __restrict__ x, const float* __restrict__ g,
               const float* __restrict__ b, float* __restrict__ o) {
    int row = blockIdx.x;
    const float* xr = x + (size_t)row * D_;
    int t = threadIdx.x;
    float v0 = xr[t], v1 = xr[t + 256], v2 = xr[t + 512];
    float s1 = v0 + v1 + v2;
    float s2 = v0 * v0 + v1 * v1 + v2 * v2;
    for (int off = 32; off > 0; off >>= 1) {
        s1 += __shfl_down(s1, off);
        s2 += __shfl_down(s2, off);
    }
    __shared__ float red[8];
    __shared__ float mv[2];
    int wave = t >> 6, lane = t & 63;
    if (lane == 0) { red[wave] = s1; red[4 + wave] = s2; }
    __syncthreads();
    if (t == 0) {
        float a = red[0] + red[1] + red[2] + red[3];
        float c = red[4] + red[5] + red[6] + red[7];
        float mean = a / (float)D_;
        float var  = c / (float)D_ - mean * mean;
        mv[0] = mean;
        mv[1] = 1.f / sqrtf(var + EPS_);
    }
    __syncthreads();
    float mean = mv[0], inv = mv[1];
    float* orow = o + (size_t)row * D_;
    orow[t]       = (v0 - mean) * inv * g[t]       + b[t];
    orow[t + 256] = (v1 - mean) * inv * g[t + 256] + b[t + 256];
    orow[t + 512] = (v2 - mean) * inv * g[t + 512] + b[t + 512];
}

// ---------------------------------------------------------------------------
// Depthwise conv (w=3) + bias + SiLU; writes fp32 xc AND hi/lo split.
// ---------------------------------------------------------------------------
__global__ __launch_bounds__(256)
void conv_silu_split_kernel(const float* __restrict__ xr, const float* __restrict__ cw,
                            const float* __restrict__ cb, float* __restrict__ xc,
                            __bf16* __restrict__ hi, __bf16* __restrict__ lo) {
    int i = blockIdx.x * 256 + threadIdx.x;
    if (i >= BLD) return;
    int d  = i % D_;
    int bl = i / D_;
    int l  = bl % L_;
    const size_t stride = 2 * D_;
    float xm = (l > 0)      ? xr[(size_t)(bl - 1) * stride + d] : 0.f;
    float x0 =                xr[(size_t)bl * stride + d];
    float xp = (l < L_ - 1) ? xr[(size_t)(bl + 1) * stride + d] : 0.f;
    float v = xm * cw[d * 3 + 0] + x0 * cw[d * 3 + 1] + xp * cw[d * 3 + 2] + cb[d];
    float s = v / (1.f + __expf(-v));
    xc[i] = s;
    __bf16 h = (__bf16)s;
    hi[i] = h;
    lo[i] = (__bf16)(s - (float)h);
}

__global__ __launch_bounds__(256)
void conv_silu_kernel(const float* __restrict__ xr, const float* __restrict__ cw,
                      const float* __restrict__ cb, float* __restrict__ xc) {
    int i = blockIdx.x * 256 + threadIdx.x;
    if (i >= BLD) return;
    int d  = i % D_;
    int bl = i / D_;
    int l  = bl % L_;
    const size_t stride = 2 * D_;
    float xm = (l > 0)      ? xr[(size_t)(bl - 1) * stride + d] : 0.f;
    float x0 =                xr[(size_t)bl * stride + d];
    float xp = (l < L_ - 1) ? xr[(size_t)(bl + 1) * stride + d] : 0.f;
    float v = xm * cw[d * 3 + 0] + x0 * cw[d * 3 + 1] + xp * cw[d * 3 + 2] + cb[d];
    xc[i] = v / (1.f + __expf(-v));
}

// ---------------------------------------------------------------------------
// Chunked parallel scan: linear recurrence h[l] = h[l-1]*dec[l] + xc[l]
// split into 8 chunks of 64; pass1 computes per-chunk (P=prod dec, H=local),
// LDS prefix combines (h_out = H + P*h_in, linear in state), pass2 rescans
// with correct h_in, reduces over s (16 lanes), writes y hi/lo split.
// Block: 256 thr = s(16) x dd(2) x chunk(8); grid = B * D/2.
// ---------------------------------------------------------------------------
__global__ __launch_bounds__(256)
void scan2_kernel(const float* __restrict__ dt, const float* __restrict__ xc,
                  const float* __restrict__ xr, const float* __restrict__ A_log,
                  const float* __restrict__ Dp, __bf16* __restrict__ yh,
                  __bf16* __restrict__ yl) {
    const int tid = threadIdx.x;
    const int s  = tid & 15;
    const int dd = (tid >> 4) & 1;
    const int c  = tid >> 5;
    const int dg = blockIdx.x % (D_ / 2);
    const int b  = blockIdx.x / (D_ / 2);
    const int d  = dg * 2 + dd;
    const float a = -__expf(A_log[d * S_ + s]);
    const int l0 = c * (L_ / 8);
    const float* dtp = dt + (size_t)b * L_ * D_ + d;
    const float* xcp = xc + (size_t)b * L_ * D_ + d;

    float P = 1.f, H = 0.f;
#pragma unroll 4
    for (int i = 0; i < L_ / 8; ++i) {
        float dtv = dtp[(size_t)(l0 + i) * D_];
        float xcv = xcp[(size_t)(l0 + i) * D_];
        float dec = __expf(a * dtv);
        P *= dec;
        H = H * dec + xcv;
    }
    __shared__ float Ps[8][2][16], Hs[8][2][16], HIn[8][2][16];
    Ps[c][dd][s] = P;
    Hs[c][dd][s] = H;
    __syncthreads();
    if (tid < 32) {
        int ss = tid & 15, d2 = tid >> 4;
        float carry = 0.f;
#pragma unroll
        for (int cc = 0; cc < 8; ++cc) {
            HIn[cc][d2][ss] = carry;
            carry = Hs[cc][d2][ss] + Ps[cc][d2][ss] * carry;
        }
    }
    __syncthreads();
    float h = HIn[c][dd][s];
    const float Dd = Dp[d];
    const float* rsp = xr + (size_t)b * L_ * 2 * D_ + D_ + d;
    size_t ybase = (size_t)b * L_ * D_ + d;
#pragma unroll 4
    for (int i = 0; i < L_ / 8; ++i) {
        int l = l0 + i;
        float dtv = dtp[(size_t)l * D_];
        float xcv = xcp[(size_t)l * D_];
        h = h * __expf(a * dtv) + xcv;
        float ys = h;
        ys += __shfl_xor(ys, 1, 16);
        ys += __shfl_xor(ys, 2, 16);
        ys += __shfl_xor(ys, 4, 16);
        ys += __shfl_xor(ys, 8, 16);
        if (s == 0) {
            float rv = rsp[(size_t)l * 2 * D_];
            float sil = rv / (1.f + __expf(-rv));
            float val = ys * Dd * sil;
            __bf16 hh = (__bf16)val;
            yh[ybase + (size_t)l * D_] = hh;
            yl[ybase + (size_t)l * D_] = (__bf16)(val - (float)hh);
        }
    }
}

// Fallback serial scan (fp32 y out)
__global__ __launch_bounds__(256)
void scan_kernel(const float* __restrict__ dt, const float* __restrict__ xc,
                 const float* __restrict__ xr, const float* __restrict__ A_log,
                 const float* __restrict__ Dp, float* __restrict__ y) {
    int t = blockIdx.x * 256 + threadIdx.x;
    int s = t & (S_ - 1);
    int d = (t >> 4) % D_;
    int b = t / (D_ * S_);
    float a  = -__expf(A_log[d * S_ + s]);
    float Dd = Dp[d];
    const float* dtp = dt + (size_t)b * L_ * D_ + d;
    const float* xcp = xc + (size_t)b * L_ * D_ + d;
    const float* rsp = xr + (size_t)b * L_ * 2 * D_ + D_ + d;
    float* yp = y + (size_t)b * L_ * D_ + d;
    float h = 0.f;
    for (int l = 0; l < L_; ++l) {
        float dtv = dtp[(size_t)l * D_];
        float xcv = xcp[(size_t)l * D_];
        h = h * __expf(a * dtv) + xcv;
        float ys = h;
        ys += __shfl_xor(ys, 1, 16);
        ys += __shfl_xor(ys, 2, 16);
        ys += __shfl_xor(ys, 4, 16);
        ys += __shfl_xor(ys, 8, 16);
        if (s == 0) {
            float rv = rsp[(size_t)l * 2 * D_];
            float sil = rv / (1.f + __expf(-rv));
            yp[(size_t)l * D_] = ys * Dd * sil;
        }
    }
}

// ---------------------------------------------------------------------------
// fp32 -> (hi, lo) bf16 split for weights. i >= n4 -> zero fill (pad).
// ---------------------------------------------------------------------------
__global__ __launch_bounds__(256)
void split4_kernel(const float* __restrict__ x, __bf16* __restrict__ hi,
                   __bf16* __restrict__ lo, int n4, int npad4) {
    int i = blockIdx.x * 256 + threadIdx.x;
    if (i >= npad4) return;
    float4 v = {0.f, 0.f, 0.f, 0.f};
    if (i < n4) v = ((const float4*)x)[i];
    bf16x4 h, l;
    h[0] = (__bf16)v.x; h[1] = (__bf16)v.y; h[2] = (__bf16)v.z; h[3] = (__bf16)v.w;
    l[0] = (__bf16)(v.x - (float)h[0]);
    l[1] = (__bf16)(v.y - (float)h[1]);
    l[2] = (__bf16)(v.z - (float)h[2]);
    l[3] = (__bf16)(v.w - (float)h[3]);
    *(bf16x4*)&hi[(size_t)i * 4] = h;
    *(bf16x4*)&lo[(size_t)i * 4] = l;
}

// ---------------------------------------------------------------------------
// 2-phase double-buffered split-bf16 MFMA GEMM.
// acc += Ahi*Whi + Alo*Whi + Ahi*Wlo per K-step; next K-tile staged via
// global_load_lds BEFORE computing current (T3-minimum recipe); ONE
// __syncthreads per K-step drains vmcnt+lgkm.
// 1D grid (pass gx = #M-blocks); m204 bijective XCD-chunk swizzle so all
// M-blocks sharing a W panel land on one XCD's L2.
// EPI: 0 plain, 1 sigmoid(v+bias), 2 v+resid.
// ---------------------------------------------------------------------------
template <int BMt, int BNt, int EPI>
__global__ __launch_bounds__(256)
void gemm3(const __bf16* __restrict__ Ahi, const __bf16* __restrict__ Alo,
           const __bf16* __restrict__ Whi, const __bf16* __restrict__ Wlo,
           const float* __restrict__ bias, const float* __restrict__ resid,
           float* __restrict__ C, int N, int K, int gx) {
    constexpr int BK  = 32;
    constexpr int FR  = BMt / 32;
    constexpr int FC  = BNt / 32;
    constexpr int ASZ = BMt * BK;   // elements per A buffer
    constexpr int WSZ = BNt * BK;
    __shared__ __bf16 Ah[2 * ASZ];
    __shared__ __bf16 Al[2 * ASZ];
    __shared__ __bf16 Wh[2 * WSZ];
    __shared__ __bf16 Wl[2 * WSZ];
    const int tid  = threadIdx.x;
    const int lane = tid & 63;
    const int wv   = tid >> 6;
    const int wr   = wv >> 1, wc = wv & 1;

    // bijective XCD-chunk swizzle (m204): hardware round-robins bid%8 over
    // XCDs; remap so each XCD owns a contiguous chunk of (M-fast) tile space.
    const int bid = blockIdx.x;
    const int nwg = gridDim.x;
    const int q = nwg >> 3, r = nwg & 7;
    const int xcd = bid & 7, lid = bid >> 3;
    const int swz = (xcd < r ? xcd * (q + 1) : r * (q + 1) + (xcd - r) * q) + lid;
    const int bm = (swz % gx) * BMt;
    const int bn = (swz / gx) * BNt;

    const int srow = tid >> 2;
    const int scol = (tid & 3) * 8;

    f32x4 acc[FR][FC] = {};

    const int arow = wr * (BMt / 2) + (lane & 15);
    const int brow = wc * (BNt / 2) + (lane & 15);
    const int kof  = (lane >> 4) * 8;

    auto STAGE = [&](int t) {
        const int k0  = t * BK;
        const int buf = t & 1;
#pragma unroll
        for (int i = 0; i < BMt / 64; ++i) {
            size_t go = (size_t)(bm + i * 64 + srow) * K + k0 + scol;
            __builtin_amdgcn_global_load_lds(
                (const __attribute__((address_space(1))) void*)(Ahi + go),
                (__attribute__((address_space(3))) void*)(Ah + buf * ASZ + i * 2048 + tid * 8),
                16, 0, 0);
            __builtin_amdgcn_global_load_lds(
                (const __attribute__((address_space(1))) void*)(Alo + go),
                (__attribute__((address_space(3))) void*)(Al + buf * ASZ + i * 2048 + tid * 8),
                16, 0, 0);
        }
#pragma unroll
        for (int i = 0; i < BNt / 64; ++i) {
            size_t go = (size_t)(bn + i * 64 + srow) * K + k0 + scol;
            __builtin_amdgcn_global_load_lds(
                (const __attribute__((address_space(1))) void*)(Whi + go),
                (__attribute__((address_space(3))) void*)(Wh + buf * WSZ + i * 2048 + tid * 8),
                16, 0, 0);
            __builtin_amdgcn_global_load_lds(
                (const __attribute__((address_space(1))) void*)(Wlo + go),
                (__attribute__((address_space(3))) void*)(Wl + buf * WSZ + i * 2048 + tid * 8),
                16, 0, 0);
        }
    };

    STAGE(0);
    const int nt = K / BK;
    for (int t = 0; t < nt; ++t) {
        __syncthreads();            // drains this wave's vmcnt (buf[t] ready)
                                    // + all waves done reading buf[t^1]
        if (t + 1 < nt) STAGE(t + 1);   // fly during compute of t
        const int buf = t & 1;
        const __bf16* Ahb = Ah + buf * ASZ;
        const __bf16* Alb = Al + buf * ASZ;
        const __bf16* Whb = Wh + buf * WSZ;
        const __bf16* Wlb = Wl + buf * WSZ;

        bf16x8 afh[FR], afl[FR], wfh[FC], wfl[FC];
#pragma unroll
        for (int f = 0; f < FR; ++f) {
            afh[f] = *(const bf16x8*)&Ahb[(arow + f * 16) * BK + kof];
            afl[f] = *(const bf16x8*)&Alb[(arow + f * 16) * BK + kof];
        }
#pragma unroll
        for (int f = 0; f < FC; ++f) {
            wfh[f] = *(const bf16x8*)&Whb[(brow + f * 16) * BK + kof];
            wfl[f] = *(const bf16x8*)&Wlb[(brow + f * 16) * BK + kof];
        }
#pragma unroll
        for (int i = 0; i < FR; ++i)
#pragma unroll
            for (int j = 0; j < FC; ++j) {
                acc[i][j] = __builtin_amdgcn_mfma_f32_16x16x32_bf16(
                    afh[i], wfh[j], acc[i][j], 0, 0, 0);
                acc[i][j] = __builtin_amdgcn_mfma_f32_16x16x32_bf16(
                    afl[i], wfh[j], acc[i][j], 0, 0, 0);
                acc[i][j] = __builtin_amdgcn_mfma_f32_16x16x32_bf16(
                    afh[i], wfl[j], acc[i][j], 0, 0, 0);
            }
    }

    // epilogue: C/D frag mapping col=lane&15, row=(lane>>4)*4+reg  [m89]
    const int rbase = bm + wr * (BMt / 2) + (lane >> 4) * 4;
    const int cbase = bn + wc * (BNt / 2) + (lane & 15);
#pragma unroll
    for (int i = 0; i < FR; ++i) {
#pragma unroll
        for (int j = 0; j < FC; ++j) {
#pragma unroll
            for (int r2 = 0; r2 < 4; ++r2) {
                int row = rbase + i * 16 + r2;
                int col = cbase + j * 16;
                if (col < N) {
                    float v = acc[i][j][r2];
                    if (EPI == 1) v = 1.f / (1.f + __expf(-(v + bias[col])));
                    if (EPI == 2) v = v + resid[(size_t)row * N + col];
                    C[(size_t)row * N + col] = v;
                }
            }
        }
    }
}

// ---------------------------------------------------------------------------
// FP32 fallback GEMM — used only if ws too small.
// ---------------------------------------------------------------------------
#define BM 128
#define BN 128
#define BKF 16

template <int EPI>
__global__ __launch_bounds__(256)
void gemm_wt(const float* __restrict__ A, const float* __restrict__ W,
             const float* __restrict__ bias, const float* __restrict__ resid,
             float* __restrict__ C, int M, int N, int K) {
    __shared__ float As[BKF][BM + 4];
    __shared__ float Wsh[BKF][BN + 4];
    const int tid = threadIdx.x;
    const int bm = blockIdx.y * BM;
    const int bn = blockIdx.x * BN;
    const int tx = tid & 15, ty = tid >> 4;
    const int lrow = tid >> 1;
    const int lk   = (tid & 1) * 8;
    float acc[8][8];
#pragma unroll
    for (int i = 0; i < 8; ++i)
#pragma unroll
        for (int j = 0; j < 8; ++j) acc[i][j] = 0.f;
    for (int k0 = 0; k0 < K; k0 += BKF) {
        const float* ap = A + (size_t)(bm + lrow) * K + k0 + lk;
        float4 av0 = *(const float4*)ap;
        float4 av1 = *(const float4*)(ap + 4);
        float4 wv0 = {0, 0, 0, 0}, wv1 = {0, 0, 0, 0};
        int wrow = bn + lrow;
        if (wrow < N) {
            const float* wp = W + (size_t)wrow * K + k0 + lk;
            wv0 = *(const float4*)wp;
            wv1 = *(const float4*)(wp + 4);
        }
        __syncthreads();
        As[lk + 0][lrow] = av0.x; As[lk + 1][lrow] = av0.y;
        As[lk + 2][lrow] = av0.z; As[lk + 3][lrow] = av0.w;
        As[lk + 4][lrow] = av1.x; As[lk + 5][lrow] = av1.y;
        As[lk + 6][lrow] = av1.z; As[lk + 7][lrow] = av1.w;
        Wsh[lk + 0][lrow] = wv0.x; Wsh[lk + 1][lrow] = wv0.y;
        Wsh[lk + 2][lrow] = wv0.z; Wsh[lk + 3][lrow] = wv0.w;
        Wsh[lk + 4][lrow] = wv1.x; Wsh[lk + 5][lrow] = wv1.y;
        Wsh[lk + 6][lrow] = wv1.z; Wsh[lk + 7][lrow] = wv1.w;
        __syncthreads();
#pragma unroll
        for (int k = 0; k < BKF; ++k) {
            float4 a0 = *(const float4*)&As[k][ty * 8];
            float4 a1 = *(const float4*)&As[k][ty * 8 + 4];
            float4 w0 = *(const float4*)&Wsh[k][tx * 8];
            float4 w1 = *(const float4*)&Wsh[k][tx * 8 + 4];
            float av[8] = {a0.x, a0.y, a0.z, a0.w, a1.x, a1.y, a1.z, a1.w};
            float wv[8] = {w0.x, w0.y, w0.z, w0.w, w1.x, w1.y, w1.z, w1.w};
#pragma unroll
            for (int i = 0; i < 8; ++i)
#pragma unroll
                for (int j = 0; j < 8; ++j)
                    acc[i][j] = fmaf(av[i], wv[j], acc[i][j]);
        }
    }
#pragma unroll
    for (int i = 0; i < 8; ++i) {
        int row = bm + ty * 8 + i;
#pragma unroll
        for (int j = 0; j < 8; ++j) {
            int col = bn + tx * 8 + j;
            if (col < N) {
                float v = acc[i][j];
                if (EPI == 1) v = 1.f / (1.f + expf(-(v + bias[col])));
                if (EPI == 2) v = v + resid[(size_t)row * N + col];
                C[(size_t)row * N + col] = v;
            }
        }
    }
}

// ---------------------------------------------------------------------------
// Host launcher
// ---------------------------------------------------------------------------
extern "C" void kernel_launch(void* const* d_in, const int* in_sizes, int n_in,
                              void* d_out, int out_size, void* d_ws, size_t ws_size,
                              hipStream_t stream) {
    (void)in_sizes; (void)n_in; (void)out_size;
    const int*   tokens  = (const int*)  d_in[0];
    const float* emb     = (const float*)d_in[1];
    const float* ln_g    = (const float*)d_in[2];
    const float* ln_b    = (const float*)d_in[3];
    const float* in_w    = (const float*)d_in[4];
    const float* conv_w  = (const float*)d_in[5];
    const float* conv_b  = (const float*)d_in[6];
    const float* dt_w    = (const float*)d_in[7];
    const float* dt_b    = (const float*)d_in[8];
    const float* A_log   = (const float*)d_in[9];
    const float* D_param = (const float*)d_in[10];
    const float* out_w   = (const float*)d_in[11];
    const float* lnf_g   = (const float*)d_in[12];
    const float* lnf_b   = (const float*)d_in[13];
    const float* head_w  = (const float*)d_in[14];
    float* out = (float*)d_out;

    // ---- workspace carve ----
    char* base = (char*)d_ws;
    char* p = base;
    auto alloc = [&](size_t bytes) -> char* {
        char* r = p;
        p += (bytes + 255) & ~(size_t)255;
        return r;
    };
    float* x  = (float*)alloc((size_t)BLD * 4);
    float* xn = (float*)alloc((size_t)BLD * 4);   // fallback only
    float* xr = (float*)alloc((size_t)2 * BLD * 4);
    float* xc = (float*)alloc((size_t)BLD * 4);
    float* dt = (float*)alloc((size_t)BLD * 4);
    float* y  = xn;  // fallback alias
    size_t fb_need = (size_t)(p - base);

    __bf16* a_hi = (__bf16*)alloc((size_t)BLD * 2);
    __bf16* a_lo = (__bf16*)alloc((size_t)BLD * 2);
    const size_t INW = (size_t)NL_ * 2 * D_ * D_;
    const size_t SQW = (size_t)NL_ * D_ * D_;
    const size_t HW  = (size_t)VPAD * D_;
    __bf16* inw_hi  = (__bf16*)alloc(INW * 2);
    __bf16* inw_lo  = (__bf16*)alloc(INW * 2);
    __bf16* dtw_hi  = (__bf16*)alloc(SQW * 2);
    __bf16* dtw_lo  = (__bf16*)alloc(SQW * 2);
    __bf16* outw_hi = (__bf16*)alloc(SQW * 2);
    __bf16* outw_lo = (__bf16*)alloc(SQW * 2);
    __bf16* hw_hi   = (__bf16*)alloc(HW * 2);
    __bf16* hw_lo   = (__bf16*)alloc(HW * 2);
    size_t fast_need = (size_t)(p - base);

    const bool fast = ws_size >= fast_need && fb_need <= ws_size;

    emb_kernel<<<(BLD + 255) / 256, 256, 0, stream>>>(tokens, emb, x);

    if (fast) {
        // weight splits (inputs restored every call -> must re-split)
        int n4;
        n4 = (int)(INW / 4);
        split4_kernel<<<(n4 + 255) / 256, 256, 0, stream>>>(in_w, inw_hi, inw_lo, n4, n4);
        n4 = (int)(SQW / 4);
        split4_kernel<<<(n4 + 255) / 256, 256, 0, stream>>>(dt_w, dtw_hi, dtw_lo, n4, n4);
        split4_kernel<<<(n4 + 255) / 256, 256, 0, stream>>>(out_w, outw_hi, outw_lo, n4, n4);
        {
            int hn4 = (int)((size_t)V_ * D_ / 4), hp4 = (int)(HW / 4);
            split4_kernel<<<(hp4 + 255) / 256, 256, 0, stream>>>(head_w, hw_hi, hw_lo, hn4, hp4);
        }

        for (int l = 0; l < NL_; ++l) {
            const float* lg = ln_g + (size_t)l * D_;
            const float* lb = ln_b + (size_t)l * D_;
            const float* cw = conv_w + (size_t)l * D_ * 3;
            const float* cb = conv_b + (size_t)l * D_;
            const float* db = dt_b + (size_t)l * D_;
            const float* al = A_log + (size_t)l * D_ * S_;
            const float* dp = D_param + (size_t)l * D_;
            const __bf16* iwh = inw_hi + (size_t)l * 2 * D_ * D_;
            const __bf16* iwl = inw_lo + (size_t)l * 2 * D_ * D_;
            const __bf16* dwh = dtw_hi + (size_t)l * D_ * D_;
            const __bf16* dwl = dtw_lo + (size_t)l * D_ * D_;
            const __bf16* owh = outw_hi + (size_t)l * D_ * D_;
            const __bf16* owl = outw_lo + (size_t)l * D_ * D_;

            ln_split_kernel<<<ROWS, 256, 0, stream>>>(x, lg, lb, a_hi, a_lo);
            // in_proj: M=1024 N=1536 K=768; grid 16 x 12 (1D, M-fast)
            gemm3<64, 128, 0><<<(ROWS / 64) * (2 * D_ / 128), 256, 0, stream>>>(
                a_hi, a_lo, iwh, iwl, nullptr, nullptr, xr, 2 * D_, D_, ROWS / 64);
            conv_silu_split_kernel<<<(BLD + 255) / 256, 256, 0, stream>>>(
                xr, cw, cb, xc, a_hi, a_lo);
            // dt: M=1024 N=768 K=768; 64x64 tiles -> 16 x 12 = 192 blocks
            gemm3<64, 64, 1><<<(ROWS / 64) * (D_ / 64), 256, 0, stream>>>(
                a_hi, a_lo, dwh, dwl, db, nullptr, dt, D_, D_, ROWS / 64);
            scan2_kernel<<<B_ * (D_ / 2), 256, 0, stream>>>(
                dt, xc, xr, al, dp, a_hi, a_lo);
            gemm3<64, 64, 2><<<(ROWS / 64) * (D_ / 64), 256, 0, stream>>>(
                a_hi, a_lo, owh, owl, nullptr, x, x, D_, D_, ROWS / 64);
        }

        ln_split_kernel<<<ROWS, 256, 0, stream>>>(x, lnf_g, lnf_b, a_hi, a_lo);
        // head: M=1024 N=50304(pad) K=768; grid 8 x 393 = 3144 (1D, M-fast)
        gemm3<128, 128, 0><<<(ROWS / 128) * (VPAD / 128), 256, 0, stream>>>(
            a_hi, a_lo, hw_hi, hw_lo, nullptr, nullptr, out, V_, D_, ROWS / 128);
    } else {
        // fp32 fallback (round-1 path)
        for (int l = 0; l < NL_; ++l) {
            const float* lg = ln_g + (size_t)l * D_;
            const float* lb = ln_b + (size_t)l * D_;
            const float* iw = in_w + (size_t)l * 2 * D_ * D_;
            const float* cw = conv_w + (size_t)l * D_ * 3;
            const float* cb = conv_b + (size_t)l * D_;
            const float* dw = dt_w + (size_t)l * D_ * D_;
            const float* db = dt_b + (size_t)l * D_;
            const float* al = A_log + (size_t)l * D_ * S_;
            const float* dp = D_param + (size_t)l * D_;
            const float* ow = out_w + (size_t)l * D_ * D_;
            ln_kernel<<<ROWS, 256, 0, stream>>>(x, lg, lb, xn);
            gemm_wt<0><<<dim3((2 * D_) / BN, ROWS / BM), 256, 0, stream>>>(
                xn, iw, nullptr, nullptr, xr, ROWS, 2 * D_, D_);
            conv_silu_kernel<<<(BLD + 255) / 256, 256, 0, stream>>>(xr, cw, cb, xc);
            gemm_wt<1><<<dim3(D_ / BN, ROWS / BM), 256, 0, stream>>>(
                xc, dw, db, nullptr, dt, ROWS, D_, D_);
            scan_kernel<<<(B_ * D_ * S_) / 256, 256, 0, stream>>>(
                dt, xc, xr, al, dp, y);
            gemm_wt<2><<<dim3(D_ / BN, ROWS / BM), 256, 0, stream>>>(
                y, ow, nullptr, x, x, ROWS, D_, D_);
        }
        ln_kernel<<<ROWS, 256, 0, stream>>>(x, lnf_g, lnf_b, xn);
        gemm_wt<0><<<dim3((V_ + BN - 1) / BN, ROWS / BM), 256, 0, stream>>>(
            xn, head_w, nullptr, nullptr, out, ROWS, V_, D_);
    }
}

// Round 7
// 1171.328 us; speedup vs baseline: 3.2738x; 1.0865x over previous
//
#include <hip/hip_runtime.h>
#include <math.h>

#define V_  50257
#define D_  768
#define S_  16
#define NL_ 4
#define B_  2
#define L_  512
#define EPS_ 1e-5f

static constexpr int BLD  = B_ * L_ * D_;     // 786432
static constexpr int ROWS = B_ * L_;          // 1024
static constexpr int VPAD = 50304;            // V_ rounded up to 128

typedef __bf16 bf16x8 __attribute__((ext_vector_type(8)));
typedef __bf16 bf16x4 __attribute__((ext_vector_type(4)));
typedef float  f32x4  __attribute__((ext_vector_type(4)));

// ---------------------------------------------------------------------------
// Embedding gather (fallback path)
// ---------------------------------------------------------------------------
__global__ __launch_bounds__(256)
void emb_kernel(const int* __restrict__ tok, const float* __restrict__ emb,
                float* __restrict__ x) {
    int i = blockIdx.x * 256 + threadIdx.x;
    if (i >= BLD) return;
    int d  = i % D_;
    int bl = i / D_;
    x[i] = emb[(size_t)tok[bl] * D_ + d];
}

// ---------------------------------------------------------------------------
// Fused: embedding gather + LayerNorm(layer0) + hi/lo split. Writes x too.
// ---------------------------------------------------------------------------
__global__ __launch_bounds__(256)
void emb_ln_split_kernel(const int* __restrict__ tok, const float* __restrict__ emb,
                         const float* __restrict__ g, const float* __restrict__ b,
                         float* __restrict__ x, __bf16* __restrict__ hi,
                         __bf16* __restrict__ lo) {
    int row = blockIdx.x;
    const float* er = emb + (size_t)tok[row] * D_;
    int t = threadIdx.x;
    float v0 = er[t], v1 = er[t + 256], v2 = er[t + 512];
    float s1 = v0 + v1 + v2;
    float s2 = v0 * v0 + v1 * v1 + v2 * v2;
    for (int off = 32; off > 0; off >>= 1) {
        s1 += __shfl_down(s1, off);
        s2 += __shfl_down(s2, off);
    }
    __shared__ float red[8];
    __shared__ float mv[2];
    int wave = t >> 6, lane = t & 63;
    if (lane == 0) { red[wave] = s1; red[4 + wave] = s2; }
    __syncthreads();
    if (t == 0) {
        float a = red[0] + red[1] + red[2] + red[3];
        float c = red[4] + red[5] + red[6] + red[7];
        float mean = a / (float)D_;
        float var  = c / (float)D_ - mean * mean;
        mv[0] = mean;
        mv[1] = 1.f / sqrtf(var + EPS_);
    }
    __syncthreads();
    float mean = mv[0], inv = mv[1];
    size_t o = (size_t)row * D_;
#pragma unroll
    for (int q = 0; q < 3; ++q) {
        int c = t + q * 256;
        float v = (q == 0 ? v0 : q == 1 ? v1 : v2);
        x[o + c] = v;
        float n = (v - mean) * inv * g[c] + b[c];
        __bf16 h = (__bf16)n;
        hi[o + c] = h;
        lo[o + c] = (__bf16)(n - (float)h);
    }
}

// ---------------------------------------------------------------------------
// LayerNorm + hi/lo split
// ---------------------------------------------------------------------------
__global__ __launch_bounds__(256)
void ln_split_kernel(const float* __restrict__ x, const float* __restrict__ g,
                     const float* __restrict__ b, __bf16* __restrict__ hi,
                     __bf16* __restrict__ lo) {
    int row = blockIdx.x;
    const float* xr = x + (size_t)row * D_;
    int t = threadIdx.x;
    float v0 = xr[t], v1 = xr[t + 256], v2 = xr[t + 512];
    float s1 = v0 + v1 + v2;
    float s2 = v0 * v0 + v1 * v1 + v2 * v2;
    for (int off = 32; off > 0; off >>= 1) {
        s1 += __shfl_down(s1, off);
        s2 += __shfl_down(s2, off);
    }
    __shared__ float red[8];
    __shared__ float mv[2];
    int wave = t >> 6, lane = t & 63;
    if (lane == 0) { red[wave] = s1; red[4 + wave] = s2; }
    __syncthreads();
    if (t == 0) {
        float a = red[0] + red[1] + red[2] + red[3];
        float c = red[4] + red[5] + red[6] + red[7];
        float mean = a / (float)D_;
        float var  = c / (float)D_ - mean * mean;
        mv[0] = mean;
        mv[1] = 1.f / sqrtf(var + EPS_);
    }
    __syncthreads();
    float mean = mv[0], inv = mv[1];
    size_t o = (size_t)row * D_;
#pragma unroll
    for (int q = 0; q < 3; ++q) {
        int c = t + q * 256;
        float v = (q == 0 ? v0 : q == 1 ? v1 : v2);
        float n = (v - mean) * inv * g[c] + b[c];
        __bf16 h = (__bf16)n;
        hi[o + c] = h;
        lo[o + c] = (__bf16)(n - (float)h);
    }
}

// Plain LN (fallback path only)
__global__ __launch_bounds__(256)
void ln_kernel(const float* __restrict__ x, const float* __restrict__ g,
               const float* __restrict__ b, float* __restrict__ o) {
    int row = blockIdx.x;
    const float* xr = x + (size_t)row * D_;
    int t = threadIdx.x;
    float v0 = xr[t], v1 = xr[t + 256], v2 = xr[t + 512];
    float s1 = v0 + v1 + v2;
    float s2 = v0 * v0 + v1 * v1 + v2 * v2;
    for (int off = 32; off > 0; off >>= 1) {
        s1 += __shfl_down(s1, off);
        s2 += __shfl_down(s2, off);
    }
    __shared__ float red[8];
    __shared__ float mv[2];
    int wave = t >> 6, lane = t & 63;
    if (lane == 0) { red[wave] = s1; red[4 + wave] = s2; }
    __syncthreads();
    if (t == 0) {
        float a = red[0] + red[1] + red[2] + red[3];
        float c = red[4] + red[5] + red[6] + red[7];
        float mean = a / (float)D_;
        float var  = c / (float)D_ - mean * mean;
        mv[0] = mean;
        mv[1] = 1.f / sqrtf(var + EPS_);
    }
    __syncthreads();
    float mean = mv[0], inv = mv[1];
    float* orow = o + (size_t)row * D_;
    orow[t]       = (v0 - mean) * inv * g[t]       + b[t];
    orow[t + 256] = (v1 - mean) * inv * g[t + 256] + b[t + 256];
    orow[t + 512] = (v2 - mean) * inv * g[t + 512] + b[t + 512];
}

// ---------------------------------------------------------------------------
// Depthwise conv (w=3) + bias + SiLU; writes fp32 xc AND hi/lo split.
// ---------------------------------------------------------------------------
__global__ __launch_bounds__(256)
void conv_silu_split_kernel(const float* __restrict__ xr, const float* __restrict__ cw,
                            const float* __restrict__ cb, float* __restrict__ xc,
                            __bf16* __restrict__ hi, __bf16* __restrict__ lo) {
    int i = blockIdx.x * 256 + threadIdx.x;
    if (i >= BLD) return;
    int d  = i % D_;
    int bl = i / D_;
    int l  = bl % L_;
    const size_t stride = 2 * D_;
    float xm = (l > 0)      ? xr[(size_t)(bl - 1) * stride + d] : 0.f;
    float x0 =                xr[(size_t)bl * stride + d];
    float xp = (l < L_ - 1) ? xr[(size_t)(bl + 1) * stride + d] : 0.f;
    float v = xm * cw[d * 3 + 0] + x0 * cw[d * 3 + 1] + xp * cw[d * 3 + 2] + cb[d];
    float s = v / (1.f + __expf(-v));
    xc[i] = s;
    __bf16 h = (__bf16)s;
    hi[i] = h;
    lo[i] = (__bf16)(s - (float)h);
}

__global__ __launch_bounds__(256)
void conv_silu_kernel(const float* __restrict__ xr, const float* __restrict__ cw,
                      const float* __restrict__ cb, float* __restrict__ xc) {
    int i = blockIdx.x * 256 + threadIdx.x;
    if (i >= BLD) return;
    int d  = i % D_;
    int bl = i / D_;
    int l  = bl % L_;
    const size_t stride = 2 * D_;
    float xm = (l > 0)      ? xr[(size_t)(bl - 1) * stride + d] : 0.f;
    float x0 =                xr[(size_t)bl * stride + d];
    float xp = (l < L_ - 1) ? xr[(size_t)(bl + 1) * stride + d] : 0.f;
    float v = xm * cw[d * 3 + 0] + x0 * cw[d * 3 + 1] + xp * cw[d * 3 + 2] + cb[d];
    xc[i] = v / (1.f + __expf(-v));
}

// ---------------------------------------------------------------------------
// scan3: chunked parallel scan, 512 thr = s(16) x dd(2) x chunk(16).
// Pass1 caches dec/xc in registers (statically indexed); pass2 has zero
// global loads except the s==0 residual read. Grid = B * D/2.
// ---------------------------------------------------------------------------
__global__ __launch_bounds__(512)
void scan3_kernel(const float* __restrict__ dt, const float* __restrict__ xc,
                  const float* __restrict__ xr, const float* __restrict__ A_log,
                  const float* __restrict__ Dp, __bf16* __restrict__ yh,
                  __bf16* __restrict__ yl) {
    constexpr int NC = 16;          // chunks
    constexpr int CH = L_ / NC;     // 32
    const int tid = threadIdx.x;
    const int s  = tid & 15;
    const int dd = (tid >> 4) & 1;
    const int c  = tid >> 5;
    const int dg = blockIdx.x % (D_ / 2);
    const int b  = blockIdx.x / (D_ / 2);
    const int d  = dg * 2 + dd;
    const float a = -__expf(A_log[d * S_ + s]);
    const int l0 = c * CH;
    const float* dtp = dt + (size_t)b * L_ * D_ + d;
    const float* xcp = xc + (size_t)b * L_ * D_ + d;

    float dec[CH], xv[CH];
    float P = 1.f, H = 0.f;
#pragma unroll
    for (int i = 0; i < CH; ++i) {
        float dtv = dtp[(size_t)(l0 + i) * D_];
        float x0  = xcp[(size_t)(l0 + i) * D_];
        float de  = __expf(a * dtv);
        dec[i] = de; xv[i] = x0;
        P *= de;
        H = H * de + x0;
    }
    __shared__ float Ps[NC][2][16], Hs[NC][2][16], HIn[NC][2][16];
    Ps[c][dd][s] = P;
    Hs[c][dd][s] = H;
    __syncthreads();
    if (tid < 32) {
        int ss = tid & 15, d2 = tid >> 4;
        float carry = 0.f;
#pragma unroll
        for (int cc = 0; cc < NC; ++cc) {
            HIn[cc][d2][ss] = carry;
            carry = Hs[cc][d2][ss] + Ps[cc][d2][ss] * carry;
        }
    }
    __syncthreads();
    float h = HIn[c][dd][s];
    const float Dd = Dp[d];
    const float* rsp = xr + (size_t)b * L_ * 2 * D_ + D_ + d;
    size_t ybase = (size_t)b * L_ * D_ + d;
#pragma unroll
    for (int i = 0; i < CH; ++i) {
        h = h * dec[i] + xv[i];
        float ys = h;
        ys += __shfl_xor(ys, 1, 16);
        ys += __shfl_xor(ys, 2, 16);
        ys += __shfl_xor(ys, 4, 16);
        ys += __shfl_xor(ys, 8, 16);
        if (s == 0) {
            int l = l0 + i;
            float rv = rsp[(size_t)l * 2 * D_];
            float sil = rv / (1.f + __expf(-rv));
            float val = ys * Dd * sil;
            __bf16 hh = (__bf16)val;
            yh[ybase + (size_t)l * D_] = hh;
            yl[ybase + (size_t)l * D_] = (__bf16)(val - (float)hh);
        }
    }
}

// Fallback serial scan (fp32 y out)
__global__ __launch_bounds__(256)
void scan_kernel(const float* __restrict__ dt, const float* __restrict__ xc,
                 const float* __restrict__ xr, const float* __restrict__ A_log,
                 const float* __restrict__ Dp, float* __restrict__ y) {
    int t = blockIdx.x * 256 + threadIdx.x;
    int s = t & (S_ - 1);
    int d = (t >> 4) % D_;
    int b = t / (D_ * S_);
    float a  = -__expf(A_log[d * S_ + s]);
    float Dd = Dp[d];
    const float* dtp = dt + (size_t)b * L_ * D_ + d;
    const float* xcp = xc + (size_t)b * L_ * D_ + d;
    const float* rsp = xr + (size_t)b * L_ * 2 * D_ + D_ + d;
    float* yp = y + (size_t)b * L_ * D_ + d;
    float h = 0.f;
    for (int l = 0; l < L_; ++l) {
        float dtv = dtp[(size_t)l * D_];
        float xcv = xcp[(size_t)l * D_];
        h = h * __expf(a * dtv) + xcv;
        float ys = h;
        ys += __shfl_xor(ys, 1, 16);
        ys += __shfl_xor(ys, 2, 16);
        ys += __shfl_xor(ys, 4, 16);
        ys += __shfl_xor(ys, 8, 16);
        if (s == 0) {
            float rv = rsp[(size_t)l * 2 * D_];
            float sil = rv / (1.f + __expf(-rv));
            yp[(size_t)l * D_] = ys * Dd * sil;
        }
    }
}

// ---------------------------------------------------------------------------
// Fused weight split: all 4 weight tensors in one dispatch.
// Segment boundaries in float4 units; head pad rows zero-filled.
// ---------------------------------------------------------------------------
static constexpr int N4_IN  = (int)((size_t)NL_ * 2 * D_ * D_ / 4);   // 1179648
static constexpr int N4_SQ  = (int)((size_t)NL_ * D_ * D_ / 4);       // 589824
static constexpr int N4_HWP = (int)((size_t)VPAD * D_ / 4);           // 9658368
static constexpr int N4_HW  = (int)((size_t)V_ * D_ / 4);             // 9649344
static constexpr int T0 = N4_IN;
static constexpr int T1 = T0 + N4_SQ;
static constexpr int T2 = T1 + N4_SQ;
static constexpr int T3 = T2 + N4_HWP;

__global__ __launch_bounds__(256)
void split_all_kernel(const float* __restrict__ inw, const float* __restrict__ dtw,
                      const float* __restrict__ outw, const float* __restrict__ hw,
                      __bf16* __restrict__ inh, __bf16* __restrict__ inl,
                      __bf16* __restrict__ dth, __bf16* __restrict__ dtl,
                      __bf16* __restrict__ oth, __bf16* __restrict__ otl,
                      __bf16* __restrict__ hwh, __bf16* __restrict__ hwl) {
    int i = blockIdx.x * 256 + threadIdx.x;
    if (i >= T3) return;
    const float* src;
    __bf16 *dh, *dl;
    int j;
    bool valid = true;
    if (i < T0)      { j = i;      src = inw;  dh = inh; dl = inl; }
    else if (i < T1) { j = i - T0; src = dtw;  dh = dth; dl = dtl; }
    else if (i < T2) { j = i - T1; src = outw; dh = oth; dl = otl; }
    else             { j = i - T2; src = hw;   dh = hwh; dl = hwl;
                       valid = j < N4_HW; }
    float4 v = {0.f, 0.f, 0.f, 0.f};
    if (valid) v = ((const float4*)src)[j];
    bf16x4 h, l;
    h[0] = (__bf16)v.x; h[1] = (__bf16)v.y; h[2] = (__bf16)v.z; h[3] = (__bf16)v.w;
    l[0] = (__bf16)(v.x - (float)h[0]);
    l[1] = (__bf16)(v.y - (float)h[1]);
    l[2] = (__bf16)(v.z - (float)h[2]);
    l[3] = (__bf16)(v.w - (float)h[3]);
    *(bf16x4*)&dh[(size_t)j * 4] = h;
    *(bf16x4*)&dl[(size_t)j * 4] = l;
}

// ---------------------------------------------------------------------------
// 2-phase double-buffered split-bf16 MFMA GEMM, generic BK (32 or 64).
// acc += Ahi*Whi + Alo*Whi + Ahi*Wlo per K-step; next tile staged before
// computing current; ONE __syncthreads per K-step. 1D grid with m204
// bijective XCD-chunk swizzle. EPI: 0 plain, 1 sigmoid(v+bias), 2 v+resid.
// ---------------------------------------------------------------------------
template <int BMt, int BNt, int BK, int EPI>
__global__ __launch_bounds__(256)
void gemm3(const __bf16* __restrict__ Ahi, const __bf16* __restrict__ Alo,
           const __bf16* __restrict__ Whi, const __bf16* __restrict__ Wlo,
           const float* __restrict__ bias, const float* __restrict__ resid,
           float* __restrict__ C, int N, int K, int gx) {
    constexpr int FR  = BMt / 32;
    constexpr int FC  = BNt / 32;
    constexpr int ASZ = BMt * BK;
    constexpr int WSZ = BNt * BK;
    constexpr int NIA = ASZ / 2048;   // issues per A matrix per buffer
    constexpr int NIW = WSZ / 2048;
    __shared__ __bf16 Ah[2 * ASZ];
    __shared__ __bf16 Al[2 * ASZ];
    __shared__ __bf16 Wh[2 * WSZ];
    __shared__ __bf16 Wl[2 * WSZ];
    const int tid  = threadIdx.x;
    const int lane = tid & 63;
    const int wv   = tid >> 6;
    const int wr   = wv >> 1, wc = wv & 1;

    // m204 bijective XCD-chunk swizzle
    const int bid = blockIdx.x;
    const int nwg = gridDim.x;
    const int q = nwg >> 3, r = nwg & 7;
    const int xcd = bid & 7, lid = bid >> 3;
    const int swz = (xcd < r ? xcd * (q + 1) : r * (q + 1) + (xcd - r) * q) + lid;
    const int bm = (swz % gx) * BMt;
    const int bn = (swz / gx) * BNt;

    f32x4 acc[FR][FC] = {};

    const int arow = wr * (BMt / 2) + (lane & 15);
    const int brow = wc * (BNt / 2) + (lane & 15);
    const int kof  = (lane >> 4) * 8;

    auto STAGE = [&](int t) {
        const int k0  = t * BK;
        const int buf = t & 1;
#pragma unroll
        for (int i = 0; i < NIA; ++i) {
            int e = i * 2048 + tid * 8;          // element within [BMt][BK]
            int row = e / BK, col = e % BK;
            size_t go = (size_t)(bm + row) * K + k0 + col;
            __builtin_amdgcn_global_load_lds(
                (const __attribute__((address_space(1))) void*)(Ahi + go),
                (__attribute__((address_space(3))) void*)(Ah + buf * ASZ + e),
                16, 0, 0);
            __builtin_amdgcn_global_load_lds(
                (const __attribute__((address_space(1))) void*)(Alo + go),
                (__attribute__((address_space(3))) void*)(Al + buf * ASZ + e),
                16, 0, 0);
        }
#pragma unroll
        for (int i = 0; i < NIW; ++i) {
            int e = i * 2048 + tid * 8;
            int row = e / BK, col = e % BK;
            size_t go = (size_t)(bn + row) * K + k0 + col;
            __builtin_amdgcn_global_load_lds(
                (const __attribute__((address_space(1))) void*)(Whi + go),
                (__attribute__((address_space(3))) void*)(Wh + buf * WSZ + e),
                16, 0, 0);
            __builtin_amdgcn_global_load_lds(
                (const __attribute__((address_space(1))) void*)(Wlo + go),
                (__attribute__((address_space(3))) void*)(Wl + buf * WSZ + e),
                16, 0, 0);
        }
    };

    STAGE(0);
    const int nt = K / BK;
    for (int t = 0; t < nt; ++t) {
        __syncthreads();                 // drains STAGE(t); buf[t^1] free
        if (t + 1 < nt) STAGE(t + 1);    // fly during compute of t
        const int buf = t & 1;
        const __bf16* Ahb = Ah + buf * ASZ;
        const __bf16* Alb = Al + buf * ASZ;
        const __bf16* Whb = Wh + buf * WSZ;
        const __bf16* Wlb = Wl + buf * WSZ;

#pragma unroll
        for (int kk = 0; kk < BK; kk += 32) {
            bf16x8 afh[FR], afl[FR], wfh[FC], wfl[FC];
#pragma unroll
            for (int f = 0; f < FR; ++f) {
                afh[f] = *(const bf16x8*)&Ahb[(arow + f * 16) * BK + kk + kof];
                afl[f] = *(const bf16x8*)&Alb[(arow + f * 16) * BK + kk + kof];
            }
#pragma unroll
            for (int f = 0; f < FC; ++f) {
                wfh[f] = *(const bf16x8*)&Whb[(brow + f * 16) * BK + kk + kof];
                wfl[f] = *(const bf16x8*)&Wlb[(brow + f * 16) * BK + kk + kof];
            }
#pragma unroll
            for (int i = 0; i < FR; ++i)
#pragma unroll
                for (int j = 0; j < FC; ++j) {
                    acc[i][j] = __builtin_amdgcn_mfma_f32_16x16x32_bf16(
                        afh[i], wfh[j], acc[i][j], 0, 0, 0);
                    acc[i][j] = __builtin_amdgcn_mfma_f32_16x16x32_bf16(
                        afl[i], wfh[j], acc[i][j], 0, 0, 0);
                    acc[i][j] = __builtin_amdgcn_mfma_f32_16x16x32_bf16(
                        afh[i], wfl[j], acc[i][j], 0, 0, 0);
                }
        }
    }

    // epilogue: C/D frag mapping col=lane&15, row=(lane>>4)*4+reg  [m89]
    const int rbase = bm + wr * (BMt / 2) + (lane >> 4) * 4;
    const int cbase = bn + wc * (BNt / 2) + (lane & 15);
#pragma unroll
    for (int i = 0; i < FR; ++i) {
#pragma unroll
        for (int j = 0; j < FC; ++j) {
#pragma unroll
            for (int r2 = 0; r2 < 4; ++r2) {
                int row = rbase + i * 16 + r2;
                int col = cbase + j * 16;
                if (col < N) {
                    float v = acc[i][j][r2];
                    if (EPI == 1) v = 1.f / (1.f + __expf(-(v + bias[col])));
                    if (EPI == 2) v = v + resid[(size_t)row * N + col];
                    C[(size_t)row * N + col] = v;
                }
            }
        }
    }
}

// ---------------------------------------------------------------------------
// FP32 fallback GEMM — used only if ws too small.
// ---------------------------------------------------------------------------
#define BM 128
#define BN 128
#define BKF 16

template <int EPI>
__global__ __launch_bounds__(256)
void gemm_wt(const float* __restrict__ A, const float* __restrict__ W,
             const float* __restrict__ bias, const float* __restrict__ resid,
             float* __restrict__ C, int M, int N, int K) {
    __shared__ float As[BKF][BM + 4];
    __shared__ float Wsh[BKF][BN + 4];
    const int tid = threadIdx.x;
    const int bm = blockIdx.y * BM;
    const int bn = blockIdx.x * BN;
    const int tx = tid & 15, ty = tid >> 4;
    const int lrow = tid >> 1;
    const int lk   = (tid & 1) * 8;
    float acc[8][8];
#pragma unroll
    for (int i = 0; i < 8; ++i)
#pragma unroll
        for (int j = 0; j < 8; ++j) acc[i][j] = 0.f;
    for (int k0 = 0; k0 < K; k0 += BKF) {
        const float* ap = A + (size_t)(bm + lrow) * K + k0 + lk;
        float4 av0 = *(const float4*)ap;
        float4 av1 = *(const float4*)(ap + 4);
        float4 wv0 = {0, 0, 0, 0}, wv1 = {0, 0, 0, 0};
        int wrow = bn + lrow;
        if (wrow < N) {
            const float* wp = W + (size_t)wrow * K + k0 + lk;
            wv0 = *(const float4*)wp;
            wv1 = *(const float4*)(wp + 4);
        }
        __syncthreads();
        As[lk + 0][lrow] = av0.x; As[lk + 1][lrow] = av0.y;
        As[lk + 2][lrow] = av0.z; As[lk + 3][lrow] = av0.w;
        As[lk + 4][lrow] = av1.x; As[lk + 5][lrow] = av1.y;
        As[lk + 6][lrow] = av1.z; As[lk + 7][lrow] = av1.w;
        Wsh[lk + 0][lrow] = wv0.x; Wsh[lk + 1][lrow] = wv0.y;
        Wsh[lk + 2][lrow] = wv0.z; Wsh[lk + 3][lrow] = wv0.w;
        Wsh[lk + 4][lrow] = wv1.x; Wsh[lk + 5][lrow] = wv1.y;
        Wsh[lk + 6][lrow] = wv1.z; Wsh[lk + 7][lrow] = wv1.w;
        __syncthreads();
#pragma unroll
        for (int k = 0; k < BKF; ++k) {
            float4 a0 = *(const float4*)&As[k][ty * 8];
            float4 a1 = *(const float4*)&As[k][ty * 8 + 4];
            float4 w0 = *(const float4*)&Wsh[k][tx * 8];
            float4 w1 = *(const float4*)&Wsh[k][tx * 8 + 4];
            float av[8] = {a0.x, a0.y, a0.z, a0.w, a1.x, a1.y, a1.z, a1.w};
            float wv[8] = {w0.x, w0.y, w0.z, w0.w, w1.x, w1.y, w1.z, w1.w};
#pragma unroll
            for (int i = 0; i < 8; ++i)
#pragma unroll
                for (int j = 0; j < 8; ++j)
                    acc[i][j] = fmaf(av[i], wv[j], acc[i][j]);
        }
    }
#pragma unroll
    for (int i = 0; i < 8; ++i) {
        int row = bm + ty * 8 + i;
#pragma unroll
        for (int j = 0; j < 8; ++j) {
            int col = bn + tx * 8 + j;
            if (col < N) {
                float v = acc[i][j];
                if (EPI == 1) v = 1.f / (1.f + expf(-(v + bias[col])));
                if (EPI == 2) v = v + resid[(size_t)row * N + col];
                C[(size_t)row * N + col] = v;
            }
        }
    }
}

// ---------------------------------------------------------------------------
// Host launcher
// ---------------------------------------------------------------------------
extern "C" void kernel_launch(void* const* d_in, const int* in_sizes, int n_in,
                              void* d_out, int out_size, void* d_ws, size_t ws_size,
                              hipStream_t stream) {
    (void)in_sizes; (void)n_in; (void)out_size;
    const int*   tokens  = (const int*)  d_in[0];
    const float* emb     = (const float*)d_in[1];
    const float* ln_g    = (const float*)d_in[2];
    const float* ln_b    = (const float*)d_in[3];
    const float* in_w    = (const float*)d_in[4];
    const float* conv_w  = (const float*)d_in[5];
    const float* conv_b  = (const float*)d_in[6];
    const float* dt_w    = (const float*)d_in[7];
    const float* dt_b    = (const float*)d_in[8];
    const float* A_log   = (const float*)d_in[9];
    const float* D_param = (const float*)d_in[10];
    const float* out_w   = (const float*)d_in[11];
    const float* lnf_g   = (const float*)d_in[12];
    const float* lnf_b   = (const float*)d_in[13];
    const float* head_w  = (const float*)d_in[14];
    float* out = (float*)d_out;

    // ---- workspace carve ----
    char* base = (char*)d_ws;
    char* p = base;
    auto alloc = [&](size_t bytes) -> char* {
        char* r = p;
        p += (bytes + 255) & ~(size_t)255;
        return r;
    };
    float* x  = (float*)alloc((size_t)BLD * 4);
    float* xn = (float*)alloc((size_t)BLD * 4);   // fallback only
    float* xr = (float*)alloc((size_t)2 * BLD * 4);
    float* xc = (float*)alloc((size_t)BLD * 4);
    float* dt = (float*)alloc((size_t)BLD * 4);
    float* y  = xn;  // fallback alias
    size_t fb_need = (size_t)(p - base);

    __bf16* a_hi = (__bf16*)alloc((size_t)BLD * 2);
    __bf16* a_lo = (__bf16*)alloc((size_t)BLD * 2);
    const size_t INW = (size_t)NL_ * 2 * D_ * D_;
    const size_t SQW = (size_t)NL_ * D_ * D_;
    const size_t HW  = (size_t)VPAD * D_;
    __bf16* inw_hi  = (__bf16*)alloc(INW * 2);
    __bf16* inw_lo  = (__bf16*)alloc(INW * 2);
    __bf16* dtw_hi  = (__bf16*)alloc(SQW * 2);
    __bf16* dtw_lo  = (__bf16*)alloc(SQW * 2);
    __bf16* outw_hi = (__bf16*)alloc(SQW * 2);
    __bf16* outw_lo = (__bf16*)alloc(SQW * 2);
    __bf16* hw_hi   = (__bf16*)alloc(HW * 2);
    __bf16* hw_lo   = (__bf16*)alloc(HW * 2);
    size_t fast_need = (size_t)(p - base);

    const bool fast = ws_size >= fast_need && fb_need <= ws_size;

    if (fast) {
        // one fused weight-split dispatch
        split_all_kernel<<<(T3 + 255) / 256, 256, 0, stream>>>(
            in_w, dt_w, out_w, head_w,
            inw_hi, inw_lo, dtw_hi, dtw_lo, outw_hi, outw_lo, hw_hi, hw_lo);
        // fused embed + layer0 LN + split
        emb_ln_split_kernel<<<ROWS, 256, 0, stream>>>(
            tokens, emb, ln_g, ln_b, x, a_hi, a_lo);

        for (int l = 0; l < NL_; ++l) {
            const float* lg = ln_g + (size_t)l * D_;
            const float* lb = ln_b + (size_t)l * D_;
            const float* cw = conv_w + (size_t)l * D_ * 3;
            const float* cb = conv_b + (size_t)l * D_;
            const float* db = dt_b + (size_t)l * D_;
            const float* al = A_log + (size_t)l * D_ * S_;
            const float* dp = D_param + (size_t)l * D_;
            const __bf16* iwh = inw_hi + (size_t)l * 2 * D_ * D_;
            const __bf16* iwl = inw_lo + (size_t)l * 2 * D_ * D_;
            const __bf16* dwh = dtw_hi + (size_t)l * D_ * D_;
            const __bf16* dwl = dtw_lo + (size_t)l * D_ * D_;
            const __bf16* owh = outw_hi + (size_t)l * D_ * D_;
            const __bf16* owl = outw_lo + (size_t)l * D_ * D_;

            if (l > 0)
                ln_split_kernel<<<ROWS, 256, 0, stream>>>(x, lg, lb, a_hi, a_lo);
            // in_proj: M=1024 N=1536 K=768, BK=64
            gemm3<64, 128, 64, 0><<<(ROWS / 64) * (2 * D_ / 128), 256, 0, stream>>>(
                a_hi, a_lo, iwh, iwl, nullptr, nullptr, xr, 2 * D_, D_, ROWS / 64);
            conv_silu_split_kernel<<<(BLD + 255) / 256, 256, 0, stream>>>(
                xr, cw, cb, xc, a_hi, a_lo);
            gemm3<64, 64, 64, 1><<<(ROWS / 64) * (D_ / 64), 256, 0, stream>>>(
                a_hi, a_lo, dwh, dwl, db, nullptr, dt, D_, D_, ROWS / 64);
            scan3_kernel<<<B_ * (D_ / 2), 512, 0, stream>>>(
                dt, xc, xr, al, dp, a_hi, a_lo);
            gemm3<64, 64, 64, 2><<<(ROWS / 64) * (D_ / 64), 256, 0, stream>>>(
                a_hi, a_lo, owh, owl, nullptr, x, x, D_, D_, ROWS / 64);
        }

        ln_split_kernel<<<ROWS, 256, 0, stream>>>(x, lnf_g, lnf_b, a_hi, a_lo);
        // head: M=1024 N=50304(pad) K=768, BK=32; grid 8 x 393
        gemm3<128, 128, 32, 0><<<(ROWS / 128) * (VPAD / 128), 256, 0, stream>>>(
            a_hi, a_lo, hw_hi, hw_lo, nullptr, nullptr, out, V_, D_, ROWS / 128);
    } else {
        emb_kernel<<<(BLD + 255) / 256, 256, 0, stream>>>(tokens, emb, x);
        for (int l = 0; l < NL_; ++l) {
            const float* lg = ln_g + (size_t)l * D_;
            const float* lb = ln_b + (size_t)l * D_;
            const float* iw = in_w + (size_t)l * 2 * D_ * D_;
            const float* cw = conv_w + (size_t)l * D_ * 3;
            const float* cb = conv_b + (size_t)l * D_;
            const float* dw = dt_w + (size_t)l * D_ * D_;
            const float* db = dt_b + (size_t)l * D_;
            const float* al = A_log + (size_t)l * D_ * S_;
            const float* dp = D_param + (size_t)l * D_;
            const float* ow = out_w + (size_t)l * D_ * D_;
            ln_kernel<<<ROWS, 256, 0, stream>>>(x, lg, lb, xn);
            gemm_wt<0><<<dim3((2 * D_) / BN, ROWS / BM), 256, 0, stream>>>(
                xn, iw, nullptr, nullptr, xr, ROWS, 2 * D_, D_);
            conv_silu_kernel<<<(BLD + 255) / 256, 256, 0, stream>>>(xr, cw, cb, xc);
            gemm_wt<1><<<dim3(D_ / BN, ROWS / BM), 256, 0, stream>>>(
                xc, dw, db, nullptr, dt, ROWS, D_, D_);
            scan_kernel<<<(B_ * D_ * S_) / 256, 256, 0, stream>>>(
                dt, xc, xr, al, dp, y);
            gemm_wt<2><<<dim3(D_ / BN, ROWS / BM), 256, 0, stream>>>(
                y, ow, nullptr, x, x, ROWS, D_, D_);
        }
        ln_kernel<<<ROWS, 256, 0, stream>>>(x, lnf_g, lnf_b, xn);
        gemm_wt<0><<<dim3((V_ + BN - 1) / BN, ROWS / BM), 256, 0, stream>>>(
            xn, head_w, nullptr, nullptr, out, ROWS, V_, D_);
    }
}